// Round 4
// baseline (671.436 us; speedup 1.0000x reference)
//
#include <hip/hip_runtime.h>
#include <cstdint>
#include <cstddef>

// ---------------------------------------------------------------------------
// TransformConvCrossAttention: B=4, SQ=SK=2048, D=1024, Kconv=3
// Pipeline (fp16 compute, fp32 MFMA accumulation; runtime-detected input
// dtype bf16-vs-fp32 (probe says fp32); mask int32; OUTPUT = float32 per the
// harness rule "reference output float32 -> float*"):
//   0. probe input dtypes + mask encoding               -> flags
//   1. convert query, memory, 4 weights -> fp16          -> ws
//   2. q/k/v projections (GEMM NT + bias)               -> lin
//   3. gated depthwise conv (K=3, SAME)                 -> conv
//   4. transpose v_conv [B,SK,D] -> v_t [B,D,SK]
//   5. logits = q.k^T/32 masked (GEMM NT, fp16 scores)
//   6. row softmax                                       -> probs fp16
//   7. attn @ v  (GEMM NT: probs x v_t)                 -> attn_out
//   8. attn_out @ o_w^T + o_b (GEMM NT)                 -> d_out (fp32)
// ---------------------------------------------------------------------------

#define GLOBAL_AS __attribute__((address_space(1)))
#define LDS_AS    __attribute__((address_space(3)))

typedef _Float16 h8 __attribute__((ext_vector_type(8)));
typedef float    f4_t __attribute__((ext_vector_type(4)));
typedef unsigned short us8 __attribute__((ext_vector_type(8)));

__device__ __forceinline__ float bf2f(unsigned short u) {
    union { unsigned int i; float f; } x; x.i = ((unsigned int)u) << 16; return x.f;
}
// dtype-flag aware scalar read (flag: 1 = bf16 storage, 0 = fp32 storage)
__device__ __forceinline__ float rd(const void* p, long i, int isBf) {
    return isBf ? bf2f(((const unsigned short*)p)[i]) : ((const float*)p)[i];
}

// ---------------------------------------------------------------------------
// Dtype probe: bf16 storage of Gaussian data has ~0% insane exponent fields;
// fp32 storage read as u16 has ~41% (even u16s are mantissa garbage).
struct Probe16 { const unsigned short* p[16]; int n[16]; };

__global__ void k_detect_dtypes(Probe16 a, int* __restrict__ flags) {
    __shared__ int cnt;
    if (threadIdx.x == 0) cnt = 0;
    __syncthreads();
    const unsigned short* s = a.p[blockIdx.x];
    const int n = a.n[blockIdx.x];
    int bad = 0;
    for (int i = threadIdx.x; i < n; i += 256) {
        int e = (s[i] >> 7) & 0xFF;
        if (e >= 0x8F || (e > 0 && e <= 0x60)) bad++;  // |x|>=2^16 or 0<|x|<=2^-31
    }
    atomicAdd(&cnt, bad);
    __syncthreads();
    if (threadIdx.x == 0) flags[blockIdx.x] = (cnt * 4 > n) ? 0 : 1;
}

// ---------------------------------------------------------------------------
// Mask encoding classifier over first 4096 u32 words. Writes element width
// (1, 2, or 4 bytes). "true" is a nonzero raw word in every encoding.
__global__ void k_classify_mask(const unsigned int* __restrict__ m, int* __restrict__ flag) {
    __shared__ int vi32, vf32, vbf, vf16;
    if (threadIdx.x == 0) { vi32 = vf32 = vbf = vf16 = 0; }
    __syncthreads();
    int bi32 = 0, bf32 = 0, bbf = 0, bf16c = 0;
    for (int i = threadIdx.x; i < 4096; i += 256) {
        unsigned int w = m[i];
        if (!(w == 0u || w == 1u)) bi32++;
        if (!(w == 0u || w == 0x3F800000u)) bf32++;
        unsigned int h0 = w & 0xFFFFu, h1 = w >> 16;
        if (!((h0 == 0u || h0 == 0x3F80u) && (h1 == 0u || h1 == 0x3F80u))) bbf++;
        if (!((h0 == 0u || h0 == 0x3C00u) && (h1 == 0u || h1 == 0x3C00u))) bf16c++;
    }
    if (bi32) atomicAdd(&vi32, 1);
    if (bf32) atomicAdd(&vf32, 1);
    if (bbf)  atomicAdd(&vbf, 1);
    if (bf16c) atomicAdd(&vf16, 1);
    __syncthreads();
    if (threadIdx.x == 0) {
        int w;
        if (vi32 == 0) w = 4;        // int32 {0,1}
        else if (vf32 == 0) w = 4;   // fp32 {0,1.0f}
        else if (vbf == 0) w = 2;    // bf16 {0,1.0}
        else if (vf16 == 0) w = 2;   // fp16 {0,1.0}
        else w = 1;                  // bytes fallback
        *flag = w;
    }
}

// ---------------------------------------------------------------------------
__global__ void k_to_f16(const void* __restrict__ src, _Float16* __restrict__ dst,
                         int n8, const int* __restrict__ flag) {
    int i = blockIdx.x * blockDim.x + threadIdx.x;
    if (i >= n8) return;
    h8 d;
    if (*flag) {
        us8 s = *(const us8*)((const unsigned short*)src + (size_t)i * 8);
#pragma unroll
        for (int u = 0; u < 8; ++u) d[u] = (_Float16)bf2f(s[u]);
    } else {
        const float* f = (const float*)src + (size_t)i * 8;
        f4_t a = *(const f4_t*)f;
        f4_t b = *(const f4_t*)(f + 4);
#pragma unroll
        for (int u = 0; u < 4; ++u) { d[u] = (_Float16)a[u]; d[4 + u] = (_Float16)b[u]; }
    }
    *(h8*)(dst + (size_t)i * 8) = d;
}

// ---------------------------------------------------------------------------
// NT GEMM: C[m,n] = sum_k A[m,k]*B[n,k] (+bias[n]) ; 128x128x32 tile, 4 waves.
// MODE 0: fp16 out            MODE 1: fp16 out + bias
// MODE 2: fp32 out + bias     MODE 3: fp16 scores (scale + mask -> -60000)
template <int MODE>
__global__ __launch_bounds__(256) void k_gemm_nt(
    const _Float16* __restrict__ A, const _Float16* __restrict__ Bm,
    void* __restrict__ Cout, const void* __restrict__ bias,
    const int* __restrict__ biasFlag,
    int N, int K, long sA, long sB, long sC,
    float scale, const void* __restrict__ mask, const int* __restrict__ maskFlag) {

    __shared__ __align__(16) _Float16 As[128 * 32];
    __shared__ __align__(16) _Float16 Bs[128 * 32];

    const int tid  = threadIdx.x;
    const int wave = tid >> 6, lane = tid & 63;
    const int wm = (wave >> 1) * 64, wn = (wave & 1) * 64;
    const int lr = lane & 15, lq = lane >> 4;
    const long bz = blockIdx.z;

    const _Float16* Ab = A + bz * sA + (size_t)blockIdx.y * 128 * K;
    const _Float16* Bb = Bm + bz * sB + (size_t)blockIdx.x * 128 * K;

    f4_t acc[4][4] = {};

    // staging: chunk c in [0,512): row=c>>2, k8=(c&3)*8; lds byte off = c*16
    const int c1 = tid, c2 = tid + 256;
    const _Float16* gA1 = Ab + (size_t)(c1 >> 2) * K + (c1 & 3) * 8;
    const _Float16* gA2 = Ab + (size_t)(c2 >> 2) * K + (c2 & 3) * 8;
    const _Float16* gB1 = Bb + (size_t)(c1 >> 2) * K + (c1 & 3) * 8;
    const _Float16* gB2 = Bb + (size_t)(c2 >> 2) * K + (c2 & 3) * 8;
    _Float16* lA1 = As + c1 * 8; _Float16* lA2 = As + c2 * 8;
    _Float16* lB1 = Bs + c1 * 8; _Float16* lB2 = Bs + c2 * 8;

    for (int kb = 0; kb < K; kb += 32) {
        __builtin_amdgcn_global_load_lds((void GLOBAL_AS*)(gA1 + kb), (void LDS_AS*)lA1, 16, 0, 0);
        __builtin_amdgcn_global_load_lds((void GLOBAL_AS*)(gA2 + kb), (void LDS_AS*)lA2, 16, 0, 0);
        __builtin_amdgcn_global_load_lds((void GLOBAL_AS*)(gB1 + kb), (void LDS_AS*)lB1, 16, 0, 0);
        __builtin_amdgcn_global_load_lds((void GLOBAL_AS*)(gB2 + kb), (void LDS_AS*)lB2, 16, 0, 0);
        __syncthreads();  // compiler drains vmcnt before s_barrier

        h8 af[4], bfr[4];
#pragma unroll
        for (int i = 0; i < 4; ++i) af[i]  = *(const h8*)&As[(wm + i * 16 + lr) * 32 + lq * 8];
#pragma unroll
        for (int j = 0; j < 4; ++j) bfr[j] = *(const h8*)&Bs[(wn + j * 16 + lr) * 32 + lq * 8];
#pragma unroll
        for (int i = 0; i < 4; ++i)
#pragma unroll
            for (int j = 0; j < 4; ++j)
                acc[i][j] = __builtin_amdgcn_mfma_f32_16x16x32_f16(af[i], bfr[j], acc[i][j], 0, 0, 0);
        __syncthreads();
    }

    // epilogue: C/D layout col=lane&15, row=(lane>>4)*4+reg
    const long row0 = (long)blockIdx.y * 128 + wm + lq * 4;
    const long col0 = (long)blockIdx.x * 128 + wn + lr;

    if constexpr (MODE == 3) {
        const int mw = *maskFlag;  // mask element width in bytes: 1, 2, or 4
        _Float16* C = (_Float16*)Cout + bz * sC;
        const unsigned int*   m4 = (const unsigned int*)mask;
        const unsigned short* m2 = (const unsigned short*)mask;
        const unsigned char*  m1 = (const unsigned char*)mask;
#pragma unroll
        for (int i = 0; i < 4; ++i)
#pragma unroll
            for (int j = 0; j < 4; ++j)
#pragma unroll
                for (int r = 0; r < 4; ++r) {
                    long row = row0 + i * 16 + r;
                    long col = col0 + j * 16;
                    long midx = row * (long)N + col;
                    bool keep = (mw == 4) ? (m4[midx] != 0u)
                              : (mw == 2) ? (m2[midx] != 0u)
                                          : (m1[midx] != 0u);
                    float v = acc[i][j][r] * scale;
                    v = fminf(fmaxf(v, -60000.0f), 60000.0f);  // keep fp16-finite
                    C[row * (long)N + col] = (_Float16)(keep ? v : -60000.0f);
                }
    } else {
        float bv[4];
        if constexpr (MODE != 0) {
            const int bIs = *biasFlag;
#pragma unroll
            for (int j = 0; j < 4; ++j) bv[j] = rd(bias, col0 + j * 16, bIs);
        } else {
#pragma unroll
            for (int j = 0; j < 4; ++j) bv[j] = 0.0f;
        }
        if constexpr (MODE == 2) {
            // fp32 output (reference output dtype is float32 -> d_out is float*)
            float* C = (float*)Cout + bz * sC;
#pragma unroll
            for (int i = 0; i < 4; ++i)
#pragma unroll
                for (int j = 0; j < 4; ++j)
#pragma unroll
                    for (int r = 0; r < 4; ++r)
                        C[(row0 + i * 16 + r) * (long)N + col0 + j * 16] = acc[i][j][r] + bv[j];
        } else {
            _Float16* C = (_Float16*)Cout + bz * sC;
#pragma unroll
            for (int i = 0; i < 4; ++i)
#pragma unroll
                for (int j = 0; j < 4; ++j)
#pragma unroll
                    for (int r = 0; r < 4; ++r) {
                        float v = acc[i][j][r] + bv[j];
                        v = fminf(fmaxf(v, -65000.0f), 65000.0f);  // keep fp16-finite
                        C[(row0 + i * 16 + r) * (long)N + col0 + j * 16] = (_Float16)v;
                    }
        }
    }
}

// ---------------------------------------------------------------------------
// y = x + tanh(gate) * (dwconv3(x) + cbias), SAME zero padding along s.
__global__ void k_dwconv(const _Float16* __restrict__ x, _Float16* __restrict__ y,
                         const void* __restrict__ kern,
                         const void* __restrict__ cbias,
                         const void* __restrict__ gate,
                         const int* __restrict__ kFlag, const int* __restrict__ cbFlag,
                         int S, int D) {
    int s = blockIdx.x, b = blockIdx.y;
    int d0 = threadIdx.x * 8;
    const size_t base = ((size_t)b * S + s) * D + d0;
    const int kIs = *kFlag, cIs = *cbFlag;
    h8 zero;
#pragma unroll
    for (int u = 0; u < 8; ++u) zero[u] = (_Float16)0.0f;
    h8 xc = *(const h8*)(x + base);
    h8 xp = (s > 0)     ? *(const h8*)(x + base - D) : zero;
    h8 xn = (s < S - 1) ? *(const h8*)(x + base + D) : zero;
    // gate==0 in setup: all-zero bytes give 0.0 under any dtype interpretation
    float tg = tanhf(((const float*)gate)[0] * 0.0f + bf2f(((const unsigned short*)gate)[0]) * 0.0f
                     + rd(gate, 0, ((const unsigned int*)gate)[0] == 0u ? 1 : 0));
    h8 o;
#pragma unroll
    for (int u = 0; u < 8; ++u) {
        int d = d0 + u;
        float cv = (float)xp[u] * rd(kern, d * 3 + 0, kIs) +
                   (float)xc[u] * rd(kern, d * 3 + 1, kIs) +
                   (float)xn[u] * rd(kern, d * 3 + 2, kIs) + rd(cbias, d, cIs);
        float v = (float)xc[u] + tg * cv;
        o[u] = (_Float16)fminf(fmaxf(v, -65000.0f), 65000.0f);
    }
    *(h8*)(y + base) = o;
}

// ---------------------------------------------------------------------------
// v [B,SK,D] -> vt [B,D,SK], 64x64 tiles via LDS.
__global__ void k_transpose(const _Float16* __restrict__ v, _Float16* __restrict__ vt,
                            int SK, int D) {
    __shared__ _Float16 T[64][65];
    int b = blockIdx.z;
    int s0 = blockIdx.x * 64, d0 = blockIdx.y * 64;
    int tid = threadIdx.x;
#pragma unroll
    for (int it = 0; it < 2; ++it) {
        int idx = it * 256 + tid;
        int r = idx >> 3, c = (idx & 7) * 8;
        h8 val = *(const h8*)(v + ((size_t)b * SK + s0 + r) * D + d0 + c);
#pragma unroll
        for (int u = 0; u < 8; ++u) T[r][c + u] = val[u];
    }
    __syncthreads();
#pragma unroll
    for (int it = 0; it < 2; ++it) {
        int idx = it * 256 + tid;
        int dr = idx >> 3, c = (idx & 7) * 8;  // c: s-offset
        h8 o;
#pragma unroll
        for (int u = 0; u < 8; ++u) o[u] = T[c + u][dr];
        *(h8*)(vt + ((size_t)b * D + d0 + dr) * SK + s0 + c) = o;
    }
}

// ---------------------------------------------------------------------------
// Row softmax over SK=2048 fp16 scores; one 256-thread block per row.
__global__ __launch_bounds__(256) void k_softmax(const _Float16* __restrict__ sc,
                                                 _Float16* __restrict__ pr, int SK) {
    const long row = blockIdx.x;
    const int tid = threadIdx.x, lane = tid & 63, wave = tid >> 6;
    h8 v = *(const h8*)(sc + row * (long)SK + tid * 8);
    float f[8]; float mx = -3.0e38f;
#pragma unroll
    for (int u = 0; u < 8; ++u) { f[u] = (float)v[u]; mx = fmaxf(mx, f[u]); }
#pragma unroll
    for (int o = 32; o > 0; o >>= 1) mx = fmaxf(mx, __shfl_xor(mx, o, 64));
    __shared__ float red[8];
    if (lane == 0) red[wave] = mx;
    __syncthreads();
    mx = fmaxf(fmaxf(red[0], red[1]), fmaxf(red[2], red[3]));
    float sum = 0.0f;
#pragma unroll
    for (int u = 0; u < 8; ++u) { f[u] = __expf(f[u] - mx); sum += f[u]; }
#pragma unroll
    for (int o = 32; o > 0; o >>= 1) sum += __shfl_xor(sum, o, 64);
    if (lane == 0) red[4 + wave] = sum;
    __syncthreads();
    sum = red[4] + red[5] + red[6] + red[7];
    float inv = 1.0f / sum;
    h8 o8;
#pragma unroll
    for (int u = 0; u < 8; ++u) o8[u] = (_Float16)(f[u] * inv);
    *(h8*)(pr + row * (long)SK + tid * 8) = o8;
}

// ---------------------------------------------------------------------------
extern "C" void kernel_launch(void* const* d_in, const int* in_sizes, int n_in,
                              void* d_out, int out_size, void* d_ws, size_t ws_size,
                              hipStream_t stream) {
    const int Bn = 4, SQ = 2048, SK = 2048, D = 1024;
    const size_t nQ = (size_t)Bn * SQ * D;   // 8,388,608

    const void* qh = d_in[0];
    const void* mh = d_in[1];
    const void* mask = d_in[2];
    const void* q_w = d_in[3];
    const void* q_b = d_in[4];
    const void* k_w = d_in[5];
    const void* k_b = d_in[6];
    const void* v_w = d_in[7];
    const void* v_b = d_in[8];
    const void* o_w = d_in[9];
    const void* o_b = d_in[10];
    const void* q_kern = d_in[11];
    const void* q_cb   = d_in[12];
    const void* q_g    = d_in[13];
    const void* k_kern = d_in[14];
    const void* k_cb   = d_in[15];
    const void* k_g    = d_in[16];
    const void* v_kern = d_in[17];
    const void* v_cb   = d_in[18];
    const void* v_g    = d_in[19];

    // ---- workspace layout (lifetime-overlaid) ----
    char* ws = (char*)d_ws;
    _Float16* scores   = (_Float16*)(ws + 0);            // fp16 scores (33.5MB)
    _Float16* attn_out = (_Float16*)(ws + 0);            // overlays scores after softmax
    _Float16* w16      = (_Float16*)(ws + 33554432);     // 4x DxD fp16 (8.4MB)
    _Float16* lin      = (_Float16*)(ws + 41943040);     // 3x [B,S,D] fp16 (50.3MB)
    _Float16* probs    = lin;                            // overlays lin after conv
    _Float16* vt       = (_Float16*)(ws + 75497472);     // [B,D,SK] fp16 (16.8MB)
    _Float16* conv     = (_Float16*)(ws + 92274688);     // 3x [B,S,D] fp16 (50.3MB)
    _Float16* qh16     = conv;                           // staging (dead before conv_q write)
    _Float16* mh16     = conv + nQ;                      // staging (dead before conv_k write)
    int*      flags    = (int*)(ws + 142606336);         // [0..15] dtype, [16] mask width

    // 0. probes
    Probe16 pa;
    const void* pp[16] = {qh, mh, q_w, k_w, v_w, o_w, q_kern, k_kern, v_kern,
                          q_b, k_b, v_b, o_b, q_cb, k_cb, v_cb};
    const int   pn[16] = {2048, 2048, 2048, 2048, 2048, 2048, 3072, 3072, 3072,
                          1024, 1024, 1024, 1024, 1024, 1024, 1024};
    for (int i = 0; i < 16; ++i) { pa.p[i] = (const unsigned short*)pp[i]; pa.n[i] = pn[i]; }
    k_detect_dtypes<<<16, 256, 0, stream>>>(pa, flags);
    k_classify_mask<<<1, 256, 0, stream>>>((const unsigned int*)mask, flags + 16);

    // 1. converts -> fp16
    k_to_f16<<<(int)(nQ / 8 / 256), 256, 0, stream>>>(qh, qh16, (int)(nQ / 8), flags + 0);
    k_to_f16<<<(int)(nQ / 8 / 256), 256, 0, stream>>>(mh, mh16, (int)(nQ / 8), flags + 1);
    const int nW8 = D * D / 8;  // 131072
    k_to_f16<<<nW8 / 256, 256, 0, stream>>>(q_w, w16 + 0 * (size_t)D * D, nW8, flags + 2);
    k_to_f16<<<nW8 / 256, 256, 0, stream>>>(k_w, w16 + 1 * (size_t)D * D, nW8, flags + 3);
    k_to_f16<<<nW8 / 256, 256, 0, stream>>>(v_w, w16 + 2 * (size_t)D * D, nW8, flags + 4);
    k_to_f16<<<nW8 / 256, 256, 0, stream>>>(o_w, w16 + 3 * (size_t)D * D, nW8, flags + 5);

    // 2. projections: M=8192, N=1024, K=1024
    dim3 g1(D / 128, (Bn * SQ) / 128, 1);
    k_gemm_nt<1><<<g1, 256, 0, stream>>>(qh16, w16 + 0 * (size_t)D * D, lin + 0 * nQ, q_b,
                                         flags + 9, D, D, 0, 0, 0, 1.0f, nullptr, nullptr);
    k_gemm_nt<1><<<g1, 256, 0, stream>>>(mh16, w16 + 1 * (size_t)D * D, lin + 1 * nQ, k_b,
                                         flags + 10, D, D, 0, 0, 0, 1.0f, nullptr, nullptr);
    k_gemm_nt<1><<<g1, 256, 0, stream>>>(mh16, w16 + 2 * (size_t)D * D, lin + 2 * nQ, v_b,
                                         flags + 11, D, D, 0, 0, 0, 1.0f, nullptr, nullptr);

    // 3. gated depthwise conv
    dim3 gc(SQ, Bn);
    k_dwconv<<<gc, 128, 0, stream>>>(lin + 0 * nQ, conv + 0 * nQ, q_kern, q_cb, q_g,
                                     flags + 6, flags + 13, SQ, D);
    k_dwconv<<<gc, 128, 0, stream>>>(lin + 1 * nQ, conv + 1 * nQ, k_kern, k_cb, k_g,
                                     flags + 7, flags + 14, SK, D);
    k_dwconv<<<gc, 128, 0, stream>>>(lin + 2 * nQ, conv + 2 * nQ, v_kern, v_cb, v_g,
                                     flags + 8, flags + 15, SK, D);

    // 4. transpose v
    dim3 gt(SK / 64, D / 64, Bn);
    k_transpose<<<gt, 256, 0, stream>>>(conv + 2 * nQ, vt, SK, D);

    // 5. scores: per-batch M=2048, N=2048, K=1024; scale=1/sqrt(D); mask
    dim3 gs(SK / 128, SQ / 128, Bn);
    k_gemm_nt<3><<<gs, 256, 0, stream>>>(conv + 0 * nQ, conv + 1 * nQ, scores, nullptr, nullptr,
                                         SK, D, (long)SQ * D, (long)SK * D, (long)SQ * SK,
                                         0.03125f, mask, flags + 16);

    // 6. softmax
    k_softmax<<<Bn * SQ, 256, 0, stream>>>(scores, probs, SK);

    // 7. attn @ v: per-batch M=2048, N=1024, K=2048
    dim3 gp(D / 128, SQ / 128, Bn);
    k_gemm_nt<0><<<gp, 256, 0, stream>>>(probs, vt, attn_out, nullptr, nullptr,
                                         D, SK, (long)SQ * SK, (long)D * SK, (long)SQ * D,
                                         1.0f, nullptr, nullptr);

    // 8. output projection: M=8192, N=1024, K=1024 -> fp32 d_out
    k_gemm_nt<2><<<g1, 256, 0, stream>>>(attn_out, w16 + 3 * (size_t)D * D, d_out, o_b,
                                         flags + 12, D, D, 0, 0, 0, 1.0f, nullptr, nullptr);

    (void)in_sizes; (void)n_in; (void)out_size; (void)ws_size;
}

// Round 5
// 627.434 us; speedup vs baseline: 1.0701x; 1.0701x over previous
//
#include <hip/hip_runtime.h>
#include <cstdint>
#include <cstddef>

// ---------------------------------------------------------------------------
// TransformConvCrossAttention: B=4, SQ=SK=2048, D=1024, Kconv=3
// fp16 compute, fp32 MFMA accumulation; fp32 in/out (runtime-verified).
//   0. probe input dtypes + mask encoding               -> flags
//   1. convert query, memory, 4 weights -> fp16          -> ws
//   2. q/k/v projections (GEMM NT + bias)               -> lin
//   2b. pack mask -> bytes (into dead q/k weight slots)
//   3. gated depthwise conv (K=3, SAME)                 -> conv
//   4. transpose v_conv [B,SK,D] -> v_t [B,D,SK]
//   5. logits = q.k^T/32 masked (GEMM NT, fp16 scores)  [byte mask]
//   6. row softmax                                       -> probs fp16
//   7. attn @ v  (GEMM NT: probs x v_t)                 -> attn_out
//   8. attn_out @ o_w^T + o_b (GEMM NT)                 -> d_out (fp32)
// R5: byte-mask precompute (scores FETCH 90->~45MB) + LDS bank-conflict
//     swizzle (chunk = row*4 + ((seg+(row>>1))&3): 8-way -> 2-way = free).
// ---------------------------------------------------------------------------

#define GLOBAL_AS __attribute__((address_space(1)))
#define LDS_AS    __attribute__((address_space(3)))

typedef _Float16 h8 __attribute__((ext_vector_type(8)));
typedef float    f4_t __attribute__((ext_vector_type(4)));
typedef unsigned short us8 __attribute__((ext_vector_type(8)));

__device__ __forceinline__ float bf2f(unsigned short u) {
    union { unsigned int i; float f; } x; x.i = ((unsigned int)u) << 16; return x.f;
}
// dtype-flag aware scalar read (flag: 1 = bf16 storage, 0 = fp32 storage)
__device__ __forceinline__ float rd(const void* p, long i, int isBf) {
    return isBf ? bf2f(((const unsigned short*)p)[i]) : ((const float*)p)[i];
}

// ---------------------------------------------------------------------------
struct Probe16 { const unsigned short* p[16]; int n[16]; };

__global__ void k_detect_dtypes(Probe16 a, int* __restrict__ flags) {
    __shared__ int cnt;
    if (threadIdx.x == 0) cnt = 0;
    __syncthreads();
    const unsigned short* s = a.p[blockIdx.x];
    const int n = a.n[blockIdx.x];
    int bad = 0;
    for (int i = threadIdx.x; i < n; i += 256) {
        int e = (s[i] >> 7) & 0xFF;
        if (e >= 0x8F || (e > 0 && e <= 0x60)) bad++;
    }
    atomicAdd(&cnt, bad);
    __syncthreads();
    if (threadIdx.x == 0) flags[blockIdx.x] = (cnt * 4 > n) ? 0 : 1;
}

// Mask encoding classifier: writes element width (1, 2, or 4 bytes).
__global__ void k_classify_mask(const unsigned int* __restrict__ m, int* __restrict__ flag) {
    __shared__ int vi32, vf32, vbf, vf16;
    if (threadIdx.x == 0) { vi32 = vf32 = vbf = vf16 = 0; }
    __syncthreads();
    int bi32 = 0, bf32 = 0, bbf = 0, bf16c = 0;
    for (int i = threadIdx.x; i < 4096; i += 256) {
        unsigned int w = m[i];
        if (!(w == 0u || w == 1u)) bi32++;
        if (!(w == 0u || w == 0x3F800000u)) bf32++;
        unsigned int h0 = w & 0xFFFFu, h1 = w >> 16;
        if (!((h0 == 0u || h0 == 0x3F80u) && (h1 == 0u || h1 == 0x3F80u))) bbf++;
        if (!((h0 == 0u || h0 == 0x3C00u) && (h1 == 0u || h1 == 0x3C00u))) bf16c++;
    }
    if (bi32) atomicAdd(&vi32, 1);
    if (bf32) atomicAdd(&vf32, 1);
    if (bbf)  atomicAdd(&vbf, 1);
    if (bf16c) atomicAdd(&vf16, 1);
    __syncthreads();
    if (threadIdx.x == 0) {
        int w;
        if (vi32 == 0) w = 4;
        else if (vf32 == 0) w = 4;
        else if (vbf == 0) w = 2;
        else if (vf16 == 0) w = 2;
        else w = 1;
        *flag = w;
    }
}

// Pack mask (any width) to bytes: out[i] = (elem[i] != 0). 4 elems/thread.
__global__ void k_mask_bytes(const void* __restrict__ m, unsigned char* __restrict__ out,
                             long n, const int* __restrict__ widthFlag) {
    long i = ((long)blockIdx.x * 256 + threadIdx.x) * 4;
    if (i >= n) return;
    const int w = *widthFlag;
    unsigned int packed = 0;
    if (w == 4) {
        const unsigned int* p = (const unsigned int*)m;
#pragma unroll
        for (int u = 0; u < 4; ++u) packed |= (p[i + u] != 0u ? 1u : 0u) << (8 * u);
    } else if (w == 2) {
        const unsigned short* p = (const unsigned short*)m;
#pragma unroll
        for (int u = 0; u < 4; ++u) packed |= (p[i + u] != 0u ? 1u : 0u) << (8 * u);
    } else {
        const unsigned char* p = (const unsigned char*)m;
#pragma unroll
        for (int u = 0; u < 4; ++u) packed |= (p[i + u] != 0u ? 1u : 0u) << (8 * u);
    }
    *(unsigned int*)(out + i) = packed;
}

// ---------------------------------------------------------------------------
__global__ void k_to_f16(const void* __restrict__ src, _Float16* __restrict__ dst,
                         int n8, const int* __restrict__ flag) {
    int i = blockIdx.x * blockDim.x + threadIdx.x;
    if (i >= n8) return;
    h8 d;
    if (*flag) {
        us8 s = *(const us8*)((const unsigned short*)src + (size_t)i * 8);
#pragma unroll
        for (int u = 0; u < 8; ++u) d[u] = (_Float16)bf2f(s[u]);
    } else {
        const float* f = (const float*)src + (size_t)i * 8;
        f4_t a = *(const f4_t*)f;
        f4_t b = *(const f4_t*)(f + 4);
#pragma unroll
        for (int u = 0; u < 4; ++u) { d[u] = (_Float16)a[u]; d[4 + u] = (_Float16)b[u]; }
    }
    *(h8*)(dst + (size_t)i * 8) = d;
}

// ---------------------------------------------------------------------------
// NT GEMM: C[m,n] = sum_k A[m,k]*B[n,k] (+bias[n]) ; 128x128x32 tile, 4 waves.
// LDS layout swizzled: physical chunk p = row*4 + ((seg + (row>>1)) & 3),
// chunk = 16B. Fragment-read start banks: 16(lr&1) + 4((lq+(lr>>1))&3) ->
// 8 distinct banks x 2 lanes = 2-way (free, m136). Staging lane c loads
// global (row=c>>2, seg=((c&3)-(c>>3))&3): permutation within each row's
// 64B quad -> coalescing preserved; LDS dest stays base + lane*16.
// MODE 0: fp16 out            MODE 1: fp16 out + bias
// MODE 2: fp32 out + bias     MODE 3: fp16 scores (scale + byte-mask)
template <int MODE>
__global__ __launch_bounds__(256) void k_gemm_nt(
    const _Float16* __restrict__ A, const _Float16* __restrict__ Bm,
    void* __restrict__ Cout, const void* __restrict__ bias,
    const int* __restrict__ biasFlag,
    int N, int K, long sA, long sB, long sC,
    float scale, const unsigned char* __restrict__ mask8) {

    __shared__ __align__(16) _Float16 As[128 * 32];
    __shared__ __align__(16) _Float16 Bs[128 * 32];

    const int tid  = threadIdx.x;
    const int wave = tid >> 6, lane = tid & 63;
    const int wm = (wave >> 1) * 64, wn = (wave & 1) * 64;
    const int lr = lane & 15, lq = lane >> 4;
    const long bz = blockIdx.z;

    const _Float16* Ab = A + bz * sA + (size_t)blockIdx.y * 128 * K;
    const _Float16* Bb = Bm + bz * sB + (size_t)blockIdx.x * 128 * K;

    f4_t acc[4][4] = {};

    // staging: LDS slot c holds global (row=c>>2, seg=((c&3)-(c>>3))&3)
    const int c1 = tid, c2 = tid + 256;
    const int r1 = c1 >> 2, s1 = ((c1 & 3) - (c1 >> 3)) & 3;
    const int r2 = c2 >> 2, s2 = ((c2 & 3) - (c2 >> 3)) & 3;
    const _Float16* gA1 = Ab + (size_t)r1 * K + s1 * 8;
    const _Float16* gA2 = Ab + (size_t)r2 * K + s2 * 8;
    const _Float16* gB1 = Bb + (size_t)r1 * K + s1 * 8;
    const _Float16* gB2 = Bb + (size_t)r2 * K + s2 * 8;
    _Float16* lA1 = As + c1 * 8; _Float16* lA2 = As + c2 * 8;
    _Float16* lB1 = Bs + c1 * 8; _Float16* lB2 = Bs + c2 * 8;

    // fragment-read swizzled seg (independent of tile row index i)
    const int fseg = ((lq + (lr >> 1)) & 3) * 8;

    for (int kb = 0; kb < K; kb += 32) {
        __builtin_amdgcn_global_load_lds((void GLOBAL_AS*)(gA1 + kb), (void LDS_AS*)lA1, 16, 0, 0);
        __builtin_amdgcn_global_load_lds((void GLOBAL_AS*)(gA2 + kb), (void LDS_AS*)lA2, 16, 0, 0);
        __builtin_amdgcn_global_load_lds((void GLOBAL_AS*)(gB1 + kb), (void LDS_AS*)lB1, 16, 0, 0);
        __builtin_amdgcn_global_load_lds((void GLOBAL_AS*)(gB2 + kb), (void LDS_AS*)lB2, 16, 0, 0);
        __syncthreads();  // compiler drains vmcnt before s_barrier

        h8 af[4], bfr[4];
#pragma unroll
        for (int i = 0; i < 4; ++i) af[i]  = *(const h8*)&As[(wm + i * 16 + lr) * 32 + fseg];
#pragma unroll
        for (int j = 0; j < 4; ++j) bfr[j] = *(const h8*)&Bs[(wn + j * 16 + lr) * 32 + fseg];
#pragma unroll
        for (int i = 0; i < 4; ++i)
#pragma unroll
            for (int j = 0; j < 4; ++j)
                acc[i][j] = __builtin_amdgcn_mfma_f32_16x16x32_f16(af[i], bfr[j], acc[i][j], 0, 0, 0);
        __syncthreads();
    }

    // epilogue: C/D layout col=lane&15, row=(lane>>4)*4+reg
    const long row0 = (long)blockIdx.y * 128 + wm + lq * 4;
    const long col0 = (long)blockIdx.x * 128 + wn + lr;

    if constexpr (MODE == 3) {
        _Float16* C = (_Float16*)Cout + bz * sC;
#pragma unroll
        for (int i = 0; i < 4; ++i)
#pragma unroll
            for (int j = 0; j < 4; ++j)
#pragma unroll
                for (int r = 0; r < 4; ++r) {
                    long row = row0 + i * 16 + r;
                    long col = col0 + j * 16;
                    bool keep = mask8[row * (long)N + col] != 0;
                    float v = acc[i][j][r] * scale;
                    v = fminf(fmaxf(v, -60000.0f), 60000.0f);
                    C[row * (long)N + col] = (_Float16)(keep ? v : -60000.0f);
                }
    } else {
        float bv[4];
        if constexpr (MODE != 0) {
            const int bIs = *biasFlag;
#pragma unroll
            for (int j = 0; j < 4; ++j) bv[j] = rd(bias, col0 + j * 16, bIs);
        } else {
#pragma unroll
            for (int j = 0; j < 4; ++j) bv[j] = 0.0f;
        }
        if constexpr (MODE == 2) {
            float* C = (float*)Cout + bz * sC;
#pragma unroll
            for (int i = 0; i < 4; ++i)
#pragma unroll
                for (int j = 0; j < 4; ++j)
#pragma unroll
                    for (int r = 0; r < 4; ++r)
                        C[(row0 + i * 16 + r) * (long)N + col0 + j * 16] = acc[i][j][r] + bv[j];
        } else {
            _Float16* C = (_Float16*)Cout + bz * sC;
#pragma unroll
            for (int i = 0; i < 4; ++i)
#pragma unroll
                for (int j = 0; j < 4; ++j)
#pragma unroll
                    for (int r = 0; r < 4; ++r) {
                        float v = acc[i][j][r] + bv[j];
                        v = fminf(fmaxf(v, -65000.0f), 65000.0f);
                        C[(row0 + i * 16 + r) * (long)N + col0 + j * 16] = (_Float16)v;
                    }
        }
    }
}

// ---------------------------------------------------------------------------
// y = x + tanh(gate) * (dwconv3(x) + cbias), SAME zero padding along s.
__global__ void k_dwconv(const _Float16* __restrict__ x, _Float16* __restrict__ y,
                         const void* __restrict__ kern,
                         const void* __restrict__ cbias,
                         const void* __restrict__ gate,
                         const int* __restrict__ kFlag, const int* __restrict__ cbFlag,
                         int S, int D) {
    int s = blockIdx.x, b = blockIdx.y;
    int d0 = threadIdx.x * 8;
    const size_t base = ((size_t)b * S + s) * D + d0;
    const int kIs = *kFlag, cIs = *cbFlag;
    h8 zero;
#pragma unroll
    for (int u = 0; u < 8; ++u) zero[u] = (_Float16)0.0f;
    h8 xc = *(const h8*)(x + base);
    h8 xp = (s > 0)     ? *(const h8*)(x + base - D) : zero;
    h8 xn = (s < S - 1) ? *(const h8*)(x + base + D) : zero;
    // gate==0 in setup: all-zero bytes give 0.0 under any dtype interpretation
    float tg = tanhf(rd(gate, 0, ((const unsigned int*)gate)[0] == 0u ? 1 : 0));
    h8 o;
#pragma unroll
    for (int u = 0; u < 8; ++u) {
        int d = d0 + u;
        float cv = (float)xp[u] * rd(kern, d * 3 + 0, kIs) +
                   (float)xc[u] * rd(kern, d * 3 + 1, kIs) +
                   (float)xn[u] * rd(kern, d * 3 + 2, kIs) + rd(cbias, d, cIs);
        float v = (float)xc[u] + tg * cv;
        o[u] = (_Float16)fminf(fmaxf(v, -65000.0f), 65000.0f);
    }
    *(h8*)(y + base) = o;
}

// ---------------------------------------------------------------------------
// v [B,SK,D] -> vt [B,D,SK], 64x64 tiles via LDS.
__global__ void k_transpose(const _Float16* __restrict__ v, _Float16* __restrict__ vt,
                            int SK, int D) {
    __shared__ _Float16 T[64][65];
    int b = blockIdx.z;
    int s0 = blockIdx.x * 64, d0 = blockIdx.y * 64;
    int tid = threadIdx.x;
#pragma unroll
    for (int it = 0; it < 2; ++it) {
        int idx = it * 256 + tid;
        int r = idx >> 3, c = (idx & 7) * 8;
        h8 val = *(const h8*)(v + ((size_t)b * SK + s0 + r) * D + d0 + c);
#pragma unroll
        for (int u = 0; u < 8; ++u) T[r][c + u] = val[u];
    }
    __syncthreads();
#pragma unroll
    for (int it = 0; it < 2; ++it) {
        int idx = it * 256 + tid;
        int dr = idx >> 3, c = (idx & 7) * 8;
        h8 o;
#pragma unroll
        for (int u = 0; u < 8; ++u) o[u] = T[c + u][dr];
        *(h8*)(vt + ((size_t)b * D + d0 + dr) * SK + s0 + c) = o;
    }
}

// ---------------------------------------------------------------------------
// Row softmax over SK=2048 fp16 scores; one 256-thread block per row.
__global__ __launch_bounds__(256) void k_softmax(const _Float16* __restrict__ sc,
                                                 _Float16* __restrict__ pr, int SK) {
    const long row = blockIdx.x;
    const int tid = threadIdx.x, lane = tid & 63, wave = tid >> 6;
    h8 v = *(const h8*)(sc + row * (long)SK + tid * 8);
    float f[8]; float mx = -3.0e38f;
#pragma unroll
    for (int u = 0; u < 8; ++u) { f[u] = (float)v[u]; mx = fmaxf(mx, f[u]); }
#pragma unroll
    for (int o = 32; o > 0; o >>= 1) mx = fmaxf(mx, __shfl_xor(mx, o, 64));
    __shared__ float red[8];
    if (lane == 0) red[wave] = mx;
    __syncthreads();
    mx = fmaxf(fmaxf(red[0], red[1]), fmaxf(red[2], red[3]));
    float sum = 0.0f;
#pragma unroll
    for (int u = 0; u < 8; ++u) { f[u] = __expf(f[u] - mx); sum += f[u]; }
#pragma unroll
    for (int o = 32; o > 0; o >>= 1) sum += __shfl_xor(sum, o, 64);
    if (lane == 0) red[4 + wave] = sum;
    __syncthreads();
    sum = red[4] + red[5] + red[6] + red[7];
    float inv = 1.0f / sum;
    h8 o8;
#pragma unroll
    for (int u = 0; u < 8; ++u) o8[u] = (_Float16)(f[u] * inv);
    *(h8*)(pr + row * (long)SK + tid * 8) = o8;
}

// ---------------------------------------------------------------------------
extern "C" void kernel_launch(void* const* d_in, const int* in_sizes, int n_in,
                              void* d_out, int out_size, void* d_ws, size_t ws_size,
                              hipStream_t stream) {
    const int Bn = 4, SQ = 2048, SK = 2048, D = 1024;
    const size_t nQ = (size_t)Bn * SQ * D;   // 8,388,608
    const long   nM = (long)SQ * SK;         // 4,194,304 mask elements

    const void* qh = d_in[0];
    const void* mh = d_in[1];
    const void* mask = d_in[2];
    const void* q_w = d_in[3];
    const void* q_b = d_in[4];
    const void* k_w = d_in[5];
    const void* k_b = d_in[6];
    const void* v_w = d_in[7];
    const void* v_b = d_in[8];
    const void* o_w = d_in[9];
    const void* o_b = d_in[10];
    const void* q_kern = d_in[11];
    const void* q_cb   = d_in[12];
    const void* q_g    = d_in[13];
    const void* k_kern = d_in[14];
    const void* k_cb   = d_in[15];
    const void* k_g    = d_in[16];
    const void* v_kern = d_in[17];
    const void* v_cb   = d_in[18];
    const void* v_g    = d_in[19];

    // ---- workspace layout (lifetime-overlaid) ----
    char* ws = (char*)d_ws;
    _Float16* scores   = (_Float16*)(ws + 0);            // fp16 scores (33.5MB)
    _Float16* attn_out = (_Float16*)(ws + 0);            // overlays scores after softmax
    _Float16* w16      = (_Float16*)(ws + 33554432);     // 4x DxD fp16 (8.4MB)
    unsigned char* mask8 = (unsigned char*)(ws + 33554432);  // 4.19MB; overlays q/k w16
                                                             // slots AFTER q,k projections
    _Float16* lin      = (_Float16*)(ws + 41943040);     // 3x [B,S,D] fp16 (50.3MB)
    _Float16* probs    = lin;                            // overlays lin after conv
    _Float16* vt       = (_Float16*)(ws + 75497472);     // [B,D,SK] fp16 (16.8MB)
    _Float16* conv     = (_Float16*)(ws + 92274688);     // 3x [B,S,D] fp16 (50.3MB)
    _Float16* qh16     = conv;                           // staging (dead before conv_q write)
    _Float16* mh16     = conv + nQ;                      // staging (dead before conv_k write)
    int*      flags    = (int*)(ws + 142606336);         // [0..15] dtype, [16] mask width

    // 0. probes
    Probe16 pa;
    const void* pp[16] = {qh, mh, q_w, k_w, v_w, o_w, q_kern, k_kern, v_kern,
                          q_b, k_b, v_b, o_b, q_cb, k_cb, v_cb};
    const int   pn[16] = {2048, 2048, 2048, 2048, 2048, 2048, 3072, 3072, 3072,
                          1024, 1024, 1024, 1024, 1024, 1024, 1024};
    for (int i = 0; i < 16; ++i) { pa.p[i] = (const unsigned short*)pp[i]; pa.n[i] = pn[i]; }
    k_detect_dtypes<<<16, 256, 0, stream>>>(pa, flags);
    k_classify_mask<<<1, 256, 0, stream>>>((const unsigned int*)mask, flags + 16);

    // 1. converts -> fp16
    k_to_f16<<<(int)(nQ / 8 / 256), 256, 0, stream>>>(qh, qh16, (int)(nQ / 8), flags + 0);
    k_to_f16<<<(int)(nQ / 8 / 256), 256, 0, stream>>>(mh, mh16, (int)(nQ / 8), flags + 1);
    const int nW8 = D * D / 8;  // 131072
    k_to_f16<<<nW8 / 256, 256, 0, stream>>>(q_w, w16 + 0 * (size_t)D * D, nW8, flags + 2);
    k_to_f16<<<nW8 / 256, 256, 0, stream>>>(k_w, w16 + 1 * (size_t)D * D, nW8, flags + 3);
    k_to_f16<<<nW8 / 256, 256, 0, stream>>>(v_w, w16 + 2 * (size_t)D * D, nW8, flags + 4);
    k_to_f16<<<nW8 / 256, 256, 0, stream>>>(o_w, w16 + 3 * (size_t)D * D, nW8, flags + 5);

    // 2. projections: M=8192, N=1024, K=1024
    dim3 g1(D / 128, (Bn * SQ) / 128, 1);
    k_gemm_nt<1><<<g1, 256, 0, stream>>>(qh16, w16 + 0 * (size_t)D * D, lin + 0 * nQ, q_b,
                                         flags + 9, D, D, 0, 0, 0, 1.0f, nullptr);
    k_gemm_nt<1><<<g1, 256, 0, stream>>>(mh16, w16 + 1 * (size_t)D * D, lin + 1 * nQ, k_b,
                                         flags + 10, D, D, 0, 0, 0, 1.0f, nullptr);
    k_gemm_nt<1><<<g1, 256, 0, stream>>>(mh16, w16 + 2 * (size_t)D * D, lin + 2 * nQ, v_b,
                                         flags + 11, D, D, 0, 0, 0, 1.0f, nullptr);

    // 2b. pack mask to bytes into the now-dead q/k weight slots (4.19MB)
    k_mask_bytes<<<(int)(nM / 4 / 256), 256, 0, stream>>>(mask, mask8, nM, flags + 16);

    // 3. gated depthwise conv
    dim3 gc(SQ, Bn);
    k_dwconv<<<gc, 128, 0, stream>>>(lin + 0 * nQ, conv + 0 * nQ, q_kern, q_cb, q_g,
                                     flags + 6, flags + 13, SQ, D);
    k_dwconv<<<gc, 128, 0, stream>>>(lin + 1 * nQ, conv + 1 * nQ, k_kern, k_cb, k_g,
                                     flags + 7, flags + 14, SK, D);
    k_dwconv<<<gc, 128, 0, stream>>>(lin + 2 * nQ, conv + 2 * nQ, v_kern, v_cb, v_g,
                                     flags + 8, flags + 15, SK, D);

    // 4. transpose v
    dim3 gt(SK / 64, D / 64, Bn);
    k_transpose<<<gt, 256, 0, stream>>>(conv + 2 * nQ, vt, SK, D);

    // 5. scores: per-batch M=2048, N=2048, K=1024; scale=1/sqrt(D); byte mask
    dim3 gs(SK / 128, SQ / 128, Bn);
    k_gemm_nt<3><<<gs, 256, 0, stream>>>(conv + 0 * nQ, conv + 1 * nQ, scores, nullptr, nullptr,
                                         SK, D, (long)SQ * D, (long)SK * D, (long)SQ * SK,
                                         0.03125f, mask8);

    // 6. softmax
    k_softmax<<<Bn * SQ, 256, 0, stream>>>(scores, probs, SK);

    // 7. attn @ v: per-batch M=2048, N=1024, K=2048
    dim3 gp(D / 128, SQ / 128, Bn);
    k_gemm_nt<0><<<gp, 256, 0, stream>>>(probs, vt, attn_out, nullptr, nullptr,
                                         D, SK, (long)SQ * SK, (long)D * SK, (long)SQ * D,
                                         1.0f, nullptr);

    // 8. output projection: M=8192, N=1024, K=1024 -> fp32 d_out
    k_gemm_nt<2><<<g1, 256, 0, stream>>>(attn_out, w16 + 3 * (size_t)D * D, d_out, o_b,
                                         flags + 12, D, D, 0, 0, 0, 1.0f, nullptr);

    (void)in_sizes; (void)n_in; (void)out_size; (void)ws_size;
}

// Round 6
// 587.720 us; speedup vs baseline: 1.1424x; 1.0676x over previous
//
#include <hip/hip_runtime.h>
#include <cstdint>
#include <cstddef>

// ---------------------------------------------------------------------------
// TransformConvCrossAttention: B=4, SQ=SK=2048, D=1024, Kconv=3
// fp16 compute, fp32 MFMA accumulation; fp32 in/out (runtime-verified).
// R6: XCD-aware 1D grid swizzle on all GEMMs (A-tile fetched once per XCD,
//     not 8x), fused k+v projection (N=2048), merged convert kernels.
// ---------------------------------------------------------------------------

#define GLOBAL_AS __attribute__((address_space(1)))
#define LDS_AS    __attribute__((address_space(3)))

typedef _Float16 h8 __attribute__((ext_vector_type(8)));
typedef float    f4_t __attribute__((ext_vector_type(4)));
typedef unsigned short us8 __attribute__((ext_vector_type(8)));

__device__ __forceinline__ float bf2f(unsigned short u) {
    union { unsigned int i; float f; } x; x.i = ((unsigned int)u) << 16; return x.f;
}
// dtype-flag aware scalar read (flag: 1 = bf16 storage, 0 = fp32 storage)
__device__ __forceinline__ float rd(const void* p, long i, int isBf) {
    return isBf ? bf2f(((const unsigned short*)p)[i]) : ((const float*)p)[i];
}

// ---------------------------------------------------------------------------
struct Probe16 { const unsigned short* p[16]; int n[16]; };

__global__ void k_detect_dtypes(Probe16 a, int* __restrict__ flags) {
    __shared__ int cnt;
    if (threadIdx.x == 0) cnt = 0;
    __syncthreads();
    const unsigned short* s = a.p[blockIdx.x];
    const int n = a.n[blockIdx.x];
    int bad = 0;
    for (int i = threadIdx.x; i < n; i += 256) {
        int e = (s[i] >> 7) & 0xFF;
        if (e >= 0x8F || (e > 0 && e <= 0x60)) bad++;
    }
    atomicAdd(&cnt, bad);
    __syncthreads();
    if (threadIdx.x == 0) flags[blockIdx.x] = (cnt * 4 > n) ? 0 : 1;
}

// Mask encoding classifier: writes element width (1, 2, or 4 bytes).
__global__ void k_classify_mask(const unsigned int* __restrict__ m, int* __restrict__ flag) {
    __shared__ int vi32, vf32, vbf, vf16;
    if (threadIdx.x == 0) { vi32 = vf32 = vbf = vf16 = 0; }
    __syncthreads();
    int bi32 = 0, bf32 = 0, bbf = 0, bf16c = 0;
    for (int i = threadIdx.x; i < 4096; i += 256) {
        unsigned int w = m[i];
        if (!(w == 0u || w == 1u)) bi32++;
        if (!(w == 0u || w == 0x3F800000u)) bf32++;
        unsigned int h0 = w & 0xFFFFu, h1 = w >> 16;
        if (!((h0 == 0u || h0 == 0x3F80u) && (h1 == 0u || h1 == 0x3F80u))) bbf++;
        if (!((h0 == 0u || h0 == 0x3C00u) && (h1 == 0u || h1 == 0x3C00u))) bf16c++;
    }
    if (bi32) atomicAdd(&vi32, 1);
    if (bf32) atomicAdd(&vf32, 1);
    if (bbf)  atomicAdd(&vbf, 1);
    if (bf16c) atomicAdd(&vf16, 1);
    __syncthreads();
    if (threadIdx.x == 0) {
        int w;
        if (vi32 == 0) w = 4;
        else if (vf32 == 0) w = 4;
        else if (vbf == 0) w = 2;
        else if (vf16 == 0) w = 2;
        else w = 1;
        *flag = w;
    }
}

// Pack mask (any width) to bytes: out[i] = (elem[i] != 0). 4 elems/thread.
__global__ void k_mask_bytes(const void* __restrict__ m, unsigned char* __restrict__ out,
                             long n, const int* __restrict__ widthFlag) {
    long i = ((long)blockIdx.x * 256 + threadIdx.x) * 4;
    if (i >= n) return;
    const int w = *widthFlag;
    unsigned int packed = 0;
    if (w == 4) {
        const unsigned int* p = (const unsigned int*)m;
#pragma unroll
        for (int u = 0; u < 4; ++u) packed |= (p[i + u] != 0u ? 1u : 0u) << (8 * u);
    } else if (w == 2) {
        const unsigned short* p = (const unsigned short*)m;
#pragma unroll
        for (int u = 0; u < 4; ++u) packed |= (p[i + u] != 0u ? 1u : 0u) << (8 * u);
    } else {
        const unsigned char* p = (const unsigned char*)m;
#pragma unroll
        for (int u = 0; u < 4; ++u) packed |= (p[i + u] != 0u ? 1u : 0u) << (8 * u);
    }
    *(unsigned int*)(out + i) = packed;
}

// ---------------------------------------------------------------------------
__device__ __forceinline__ h8 cvt8(const void* src, size_t off8, int isBf) {
    h8 d;
    if (isBf) {
        us8 s = *(const us8*)((const unsigned short*)src + off8 * 8);
#pragma unroll
        for (int u = 0; u < 8; ++u) d[u] = (_Float16)bf2f(s[u]);
    } else {
        const float* f = (const float*)src + off8 * 8;
        f4_t a = *(const f4_t*)f;
        f4_t b = *(const f4_t*)(f + 4);
#pragma unroll
        for (int u = 0; u < 4; ++u) { d[u] = (_Float16)a[u]; d[4 + u] = (_Float16)b[u]; }
    }
    return d;
}

// Convert 2 equal-size hidden tensors into contiguous dst.
__global__ void k_h_to_f16(const void* __restrict__ s0, const void* __restrict__ s1,
                           _Float16* __restrict__ dst, int n8each,
                           const int* __restrict__ flags) {
    int i = blockIdx.x * blockDim.x + threadIdx.x;
    if (i >= 2 * n8each) return;
    int seg = i / n8each, off = i - seg * n8each;
    h8 d = cvt8(seg ? s1 : s0, off, flags[seg]);
    *(h8*)(dst + (size_t)i * 8) = d;
}

// Convert 4 weight matrices into contiguous dst (w16 slots).
struct Ptr4 { const void* p[4]; };
__global__ void k_w_to_f16(Ptr4 srcs, _Float16* __restrict__ dst, int n8each,
                           const int* __restrict__ flags) {
    int i = blockIdx.x * blockDim.x + threadIdx.x;
    if (i >= 4 * n8each) return;
    int seg = i / n8each, off = i - seg * n8each;
    h8 d = cvt8(srcs.p[seg], off, flags[seg]);
    *(h8*)(dst + (size_t)i * 8) = d;
}

// ---------------------------------------------------------------------------
// NT GEMM: C[m,n] = sum_k A[m,k]*B[n,k] (+bias[n]) ; 128x128x32 tile, 4 waves.
// 1D grid with XCD-aware decode: id -> xcd = id&7; within an XCD's
// round-robin stream, all NT col-blocks of one (row,batch) are consecutive
// -> A row-tile fetched once per XCD; g ordered (row, batch) so each XCD
// sticks to few batches -> B tiles stay L2-resident.
// LDS chunk swizzle: p = row*4 + ((seg+(row>>1))&3) -> 2-way conflicts (free).
// MODE 0: fp16 out            MODE 1: fp16 out + bias (bias2 = second N-half)
// MODE 2: fp32 out + bias     MODE 3: fp16 scores (scale + byte-mask)
template <int MODE>
__global__ __launch_bounds__(256) void k_gemm_nt(
    const _Float16* __restrict__ A, const _Float16* __restrict__ Bm,
    void* __restrict__ Cout,
    const void* __restrict__ bias, const int* __restrict__ biasFlag,
    const void* __restrict__ bias2, const int* __restrict__ biasFlag2,
    int N, int K, long sA, long sB, long sC,
    float scale, const unsigned char* __restrict__ mask8,
    int NT, int BZ) {

    __shared__ __align__(16) _Float16 As[128 * 32];
    __shared__ __align__(16) _Float16 Bs[128 * 32];

    // ---- XCD-aware block decode ----
    const long id = blockIdx.x;
    const int xcd = (int)(id & 7);
    const long local = id >> 3;
    const int col = (int)(local % NT);
    const long g = (local / NT) * 8 + xcd;
    const int bz = (int)(g % BZ);
    const int brow = (int)(g / BZ);

    const int tid  = threadIdx.x;
    const int wave = tid >> 6, lane = tid & 63;
    const int wm = (wave >> 1) * 64, wn = (wave & 1) * 64;
    const int lr = lane & 15, lq = lane >> 4;

    const _Float16* Ab = A + (long)bz * sA + (size_t)brow * 128 * K;
    const _Float16* Bb = Bm + (long)bz * sB + (size_t)col * 128 * K;

    f4_t acc[4][4] = {};

    // staging: LDS slot c holds global (row=c>>2, seg=((c&3)-(c>>3))&3)
    const int c1 = tid, c2 = tid + 256;
    const int r1 = c1 >> 2, s1 = ((c1 & 3) - (c1 >> 3)) & 3;
    const int r2 = c2 >> 2, s2 = ((c2 & 3) - (c2 >> 3)) & 3;
    const _Float16* gA1 = Ab + (size_t)r1 * K + s1 * 8;
    const _Float16* gA2 = Ab + (size_t)r2 * K + s2 * 8;
    const _Float16* gB1 = Bb + (size_t)r1 * K + s1 * 8;
    const _Float16* gB2 = Bb + (size_t)r2 * K + s2 * 8;
    _Float16* lA1 = As + c1 * 8; _Float16* lA2 = As + c2 * 8;
    _Float16* lB1 = Bs + c1 * 8; _Float16* lB2 = Bs + c2 * 8;

    // fragment-read swizzled seg (independent of tile row index i)
    const int fseg = ((lq + (lr >> 1)) & 3) * 8;

    for (int kb = 0; kb < K; kb += 32) {
        __builtin_amdgcn_global_load_lds((void GLOBAL_AS*)(gA1 + kb), (void LDS_AS*)lA1, 16, 0, 0);
        __builtin_amdgcn_global_load_lds((void GLOBAL_AS*)(gA2 + kb), (void LDS_AS*)lA2, 16, 0, 0);
        __builtin_amdgcn_global_load_lds((void GLOBAL_AS*)(gB1 + kb), (void LDS_AS*)lB1, 16, 0, 0);
        __builtin_amdgcn_global_load_lds((void GLOBAL_AS*)(gB2 + kb), (void LDS_AS*)lB2, 16, 0, 0);
        __syncthreads();

        h8 af[4], bfr[4];
#pragma unroll
        for (int i = 0; i < 4; ++i) af[i]  = *(const h8*)&As[(wm + i * 16 + lr) * 32 + fseg];
#pragma unroll
        for (int j = 0; j < 4; ++j) bfr[j] = *(const h8*)&Bs[(wn + j * 16 + lr) * 32 + fseg];
#pragma unroll
        for (int i = 0; i < 4; ++i)
#pragma unroll
            for (int j = 0; j < 4; ++j)
                acc[i][j] = __builtin_amdgcn_mfma_f32_16x16x32_f16(af[i], bfr[j], acc[i][j], 0, 0, 0);
        __syncthreads();
    }

    // epilogue: C/D layout col=lane&15, row=(lane>>4)*4+reg
    const long row0 = (long)brow * 128 + wm + lq * 4;
    const long col0 = (long)col * 128 + wn + lr;

    if constexpr (MODE == 3) {
        _Float16* C = (_Float16*)Cout + (long)bz * sC;
#pragma unroll
        for (int i = 0; i < 4; ++i)
#pragma unroll
            for (int j = 0; j < 4; ++j)
#pragma unroll
                for (int r = 0; r < 4; ++r) {
                    long row = row0 + i * 16 + r;
                    long ccol = col0 + j * 16;
                    bool keep = mask8[row * (long)N + ccol] != 0;
                    float v = acc[i][j][r] * scale;
                    v = fminf(fmaxf(v, -60000.0f), 60000.0f);
                    C[row * (long)N + ccol] = (_Float16)(keep ? v : -60000.0f);
                }
    } else {
        float bv[4];
        if constexpr (MODE != 0) {
            const void* bp = bias; const int* bfp = biasFlag; long boff = 0;
            if (bias2 != nullptr && col * 128 >= (N >> 1)) {
                bp = bias2; bfp = biasFlag2; boff = (long)(N >> 1);
            }
            const int bIs = *bfp;
#pragma unroll
            for (int j = 0; j < 4; ++j) bv[j] = rd(bp, col0 + j * 16 - boff, bIs);
        } else {
#pragma unroll
            for (int j = 0; j < 4; ++j) bv[j] = 0.0f;
        }
        if constexpr (MODE == 2) {
            float* C = (float*)Cout + (long)bz * sC;
#pragma unroll
            for (int i = 0; i < 4; ++i)
#pragma unroll
                for (int j = 0; j < 4; ++j)
#pragma unroll
                    for (int r = 0; r < 4; ++r)
                        C[(row0 + i * 16 + r) * (long)N + col0 + j * 16] = acc[i][j][r] + bv[j];
        } else {
            _Float16* C = (_Float16*)Cout + (long)bz * sC;
#pragma unroll
            for (int i = 0; i < 4; ++i)
#pragma unroll
                for (int j = 0; j < 4; ++j)
#pragma unroll
                    for (int r = 0; r < 4; ++r) {
                        float v = acc[i][j][r] + bv[j];
                        v = fminf(fmaxf(v, -65000.0f), 65000.0f);
                        C[(row0 + i * 16 + r) * (long)N + col0 + j * 16] = (_Float16)v;
                    }
        }
    }
}

// ---------------------------------------------------------------------------
// y = x + tanh(gate) * (dwconv3(x) + cbias); x has row stride xStride,
// output contiguous [B,S,D].
__global__ void k_dwconv(const _Float16* __restrict__ x, int xStride,
                         _Float16* __restrict__ y,
                         const void* __restrict__ kern,
                         const void* __restrict__ cbias,
                         const void* __restrict__ gate,
                         const int* __restrict__ kFlag, const int* __restrict__ cbFlag,
                         int S, int D) {
    int s = blockIdx.x, b = blockIdx.y;
    int d0 = threadIdx.x * 8;
    const size_t xb = ((size_t)b * S + s) * xStride + d0;
    const size_t yb = ((size_t)b * S + s) * D + d0;
    const int kIs = *kFlag, cIs = *cbFlag;
    h8 zero;
#pragma unroll
    for (int u = 0; u < 8; ++u) zero[u] = (_Float16)0.0f;
    h8 xc = *(const h8*)(x + xb);
    h8 xp = (s > 0)     ? *(const h8*)(x + xb - xStride) : zero;
    h8 xn = (s < S - 1) ? *(const h8*)(x + xb + xStride) : zero;
    float tg = tanhf(rd(gate, 0, ((const unsigned int*)gate)[0] == 0u ? 1 : 0));
    h8 o;
#pragma unroll
    for (int u = 0; u < 8; ++u) {
        int d = d0 + u;
        float cv = (float)xp[u] * rd(kern, d * 3 + 0, kIs) +
                   (float)xc[u] * rd(kern, d * 3 + 1, kIs) +
                   (float)xn[u] * rd(kern, d * 3 + 2, kIs) + rd(cbias, d, cIs);
        float v = (float)xc[u] + tg * cv;
        o[u] = (_Float16)fminf(fmaxf(v, -65000.0f), 65000.0f);
    }
    *(h8*)(y + yb) = o;
}

// ---------------------------------------------------------------------------
// v [B,SK,D] -> vt [B,D,SK], 64x64 tiles via LDS.
__global__ void k_transpose(const _Float16* __restrict__ v, _Float16* __restrict__ vt,
                            int SK, int D) {
    __shared__ _Float16 T[64][65];
    int b = blockIdx.z;
    int s0 = blockIdx.x * 64, d0 = blockIdx.y * 64;
    int tid = threadIdx.x;
#pragma unroll
    for (int it = 0; it < 2; ++it) {
        int idx = it * 256 + tid;
        int r = idx >> 3, c = (idx & 7) * 8;
        h8 val = *(const h8*)(v + ((size_t)b * SK + s0 + r) * D + d0 + c);
#pragma unroll
        for (int u = 0; u < 8; ++u) T[r][c + u] = val[u];
    }
    __syncthreads();
#pragma unroll
    for (int it = 0; it < 2; ++it) {
        int idx = it * 256 + tid;
        int dr = idx >> 3, c = (idx & 7) * 8;
        h8 o;
#pragma unroll
        for (int u = 0; u < 8; ++u) o[u] = T[c + u][dr];
        *(h8*)(vt + ((size_t)b * D + d0 + dr) * SK + s0 + c) = o;
    }
}

// ---------------------------------------------------------------------------
// Row softmax over SK=2048 fp16 scores; one 256-thread block per row.
__global__ __launch_bounds__(256) void k_softmax(const _Float16* __restrict__ sc,
                                                 _Float16* __restrict__ pr, int SK) {
    const long row = blockIdx.x;
    const int tid = threadIdx.x, lane = tid & 63, wave = tid >> 6;
    h8 v = *(const h8*)(sc + row * (long)SK + tid * 8);
    float f[8]; float mx = -3.0e38f;
#pragma unroll
    for (int u = 0; u < 8; ++u) { f[u] = (float)v[u]; mx = fmaxf(mx, f[u]); }
#pragma unroll
    for (int o = 32; o > 0; o >>= 1) mx = fmaxf(mx, __shfl_xor(mx, o, 64));
    __shared__ float red[8];
    if (lane == 0) red[wave] = mx;
    __syncthreads();
    mx = fmaxf(fmaxf(red[0], red[1]), fmaxf(red[2], red[3]));
    float sum = 0.0f;
#pragma unroll
    for (int u = 0; u < 8; ++u) { f[u] = __expf(f[u] - mx); sum += f[u]; }
#pragma unroll
    for (int o = 32; o > 0; o >>= 1) sum += __shfl_xor(sum, o, 64);
    if (lane == 0) red[4 + wave] = sum;
    __syncthreads();
    sum = red[4] + red[5] + red[6] + red[7];
    float inv = 1.0f / sum;
    h8 o8;
#pragma unroll
    for (int u = 0; u < 8; ++u) o8[u] = (_Float16)(f[u] * inv);
    *(h8*)(pr + row * (long)SK + tid * 8) = o8;
}

// ---------------------------------------------------------------------------
extern "C" void kernel_launch(void* const* d_in, const int* in_sizes, int n_in,
                              void* d_out, int out_size, void* d_ws, size_t ws_size,
                              hipStream_t stream) {
    const int Bn = 4, SQ = 2048, SK = 2048, D = 1024;
    const size_t nQ = (size_t)Bn * SQ * D;   // 8,388,608
    const long   nM = (long)SQ * SK;         // 4,194,304 mask elements

    const void* qh = d_in[0];
    const void* mh = d_in[1];
    const void* mask = d_in[2];
    const void* q_w = d_in[3];
    const void* q_b = d_in[4];
    const void* k_w = d_in[5];
    const void* k_b = d_in[6];
    const void* v_w = d_in[7];
    const void* v_b = d_in[8];
    const void* o_w = d_in[9];
    const void* o_b = d_in[10];
    const void* q_kern = d_in[11];
    const void* q_cb   = d_in[12];
    const void* q_g    = d_in[13];
    const void* k_kern = d_in[14];
    const void* k_cb   = d_in[15];
    const void* k_g    = d_in[16];
    const void* v_kern = d_in[17];
    const void* v_cb   = d_in[18];
    const void* v_g    = d_in[19];

    // ---- workspace layout (lifetime-overlaid) ----
    char* ws = (char*)d_ws;
    _Float16* scores   = (_Float16*)(ws + 0);            // fp16 scores (33.5MB)
    _Float16* attn_out = (_Float16*)(ws + 0);            // overlays scores after softmax
    _Float16* w16      = (_Float16*)(ws + 33554432);     // 4x DxD fp16 (8.4MB)
    unsigned char* mask8 = (unsigned char*)(ws + 33554432); // 4.19MB; overlays q/k w16
                                                            // slots AFTER q,kv projections
    _Float16* lin      = (_Float16*)(ws + 41943040);     // q:[B,S,D] + kv:[B,S,2D] (50.3MB)
    _Float16* lin_q    = lin;
    _Float16* lin_kv   = lin + nQ;                       // [B,S,2048] fp16 (33.5MB)
    _Float16* probs    = lin;                            // overlays lin after conv
    _Float16* vt       = (_Float16*)(ws + 75497472);     // [B,D,SK] fp16 (16.8MB)
    _Float16* conv     = (_Float16*)(ws + 92274688);     // 3x [B,S,D] fp16 (50.3MB)
    _Float16* qh16     = conv;                           // staging (dead before conv_q write)
    _Float16* mh16     = conv + nQ;                      // staging (dead before conv_k write)
    int*      flags    = (int*)(ws + 142606336);         // [0..15] dtype, [16] mask width

    // 0. probes
    Probe16 pa;
    const void* pp[16] = {qh, mh, q_w, k_w, v_w, o_w, q_kern, k_kern, v_kern,
                          q_b, k_b, v_b, o_b, q_cb, k_cb, v_cb};
    const int   pn[16] = {2048, 2048, 2048, 2048, 2048, 2048, 3072, 3072, 3072,
                          1024, 1024, 1024, 1024, 1024, 1024, 1024};
    for (int i = 0; i < 16; ++i) { pa.p[i] = (const unsigned short*)pp[i]; pa.n[i] = pn[i]; }
    k_detect_dtypes<<<16, 256, 0, stream>>>(pa, flags);
    k_classify_mask<<<1, 256, 0, stream>>>((const unsigned int*)mask, flags + 16);

    // 1. converts -> fp16 (2 kernels)
    const int nH8 = (int)(nQ / 8);           // per hidden tensor
    k_h_to_f16<<<(2 * nH8 + 255) / 256, 256, 0, stream>>>(qh, mh, qh16, nH8, flags + 0);
    const int nW8 = D * D / 8;               // 131072 per weight
    Ptr4 wp; wp.p[0] = q_w; wp.p[1] = k_w; wp.p[2] = v_w; wp.p[3] = o_w;
    k_w_to_f16<<<(4 * nW8 + 255) / 256, 256, 0, stream>>>(wp, w16, nW8, flags + 2);

    // 2. projections (XCD-swizzled 1D grids)
    //    q: M=8192, N=1024, K=1024  -> MT=64, NT=8,  BZ=1 (512 blocks)
    k_gemm_nt<1><<<dim3(512), 256, 0, stream>>>(
        qh16, w16, lin_q, q_b, flags + 9, nullptr, nullptr,
        D, D, 0, 0, 0, 1.0f, nullptr, 8, 1);
    //    kv fused: M=8192, N=2048, K=1024 -> MT=64, NT=16, BZ=1 (1024 blocks)
    k_gemm_nt<1><<<dim3(1024), 256, 0, stream>>>(
        mh16, w16 + (size_t)D * D, lin_kv, k_b, flags + 10, v_b, flags + 11,
        2 * D, D, 0, 0, 0, 1.0f, nullptr, 16, 1);

    // 2b. pack mask to bytes into the now-dead q/k weight slots (4.19MB)
    k_mask_bytes<<<(int)(nM / 4 / 256), 256, 0, stream>>>(mask, mask8, nM, flags + 16);

    // 3. gated depthwise conv (q from lin_q stride D; k/v from lin_kv stride 2D)
    dim3 gc(SQ, Bn);
    k_dwconv<<<gc, 128, 0, stream>>>(lin_q, D, conv + 0 * nQ, q_kern, q_cb, q_g,
                                     flags + 6, flags + 13, SQ, D);
    k_dwconv<<<gc, 128, 0, stream>>>(lin_kv, 2 * D, conv + 1 * nQ, k_kern, k_cb, k_g,
                                     flags + 7, flags + 14, SK, D);
    k_dwconv<<<gc, 128, 0, stream>>>(lin_kv + D, 2 * D, conv + 2 * nQ, v_kern, v_cb, v_g,
                                     flags + 8, flags + 15, SK, D);

    // 4. transpose v
    dim3 gt(SK / 64, D / 64, Bn);
    k_transpose<<<gt, 256, 0, stream>>>(conv + 2 * nQ, vt, SK, D);

    // 5. scores: per-batch M=2048, N=2048, K=1024 -> MT=16, NT=16, BZ=4 (1024)
    k_gemm_nt<3><<<dim3(1024), 256, 0, stream>>>(
        conv + 0 * nQ, conv + 1 * nQ, scores, nullptr, nullptr, nullptr, nullptr,
        SK, D, (long)SQ * D, (long)SK * D, (long)SQ * SK, 0.03125f, mask8, 16, 4);

    // 6. softmax
    k_softmax<<<Bn * SQ, 256, 0, stream>>>(scores, probs, SK);

    // 7. attn @ v: per-batch M=2048, N=1024, K=2048 -> MT=16, NT=8, BZ=4 (512)
    k_gemm_nt<0><<<dim3(512), 256, 0, stream>>>(
        probs, vt, attn_out, nullptr, nullptr, nullptr, nullptr,
        D, SK, (long)SQ * SK, (long)D * SK, (long)SQ * D, 1.0f, nullptr, 8, 4);

    // 8. output projection: M=8192, N=1024, K=1024 -> MT=64, NT=8, BZ=1 (512)
    k_gemm_nt<2><<<dim3(512), 256, 0, stream>>>(
        attn_out, w16 + 3 * (size_t)D * D, d_out, o_b, flags + 12, nullptr, nullptr,
        D, D, 0, 0, 0, 1.0f, nullptr, 8, 1);

    (void)in_sizes; (void)n_in; (void)out_size; (void)ws_size;
}

// Round 8
// 553.175 us; speedup vs baseline: 1.2138x; 1.0624x over previous
//
#include <hip/hip_runtime.h>
#include <cstdint>
#include <cstddef>

// ---------------------------------------------------------------------------
// TransformConvCrossAttention: B=4, SQ=SK=2048, D=1024, Kconv=3
// fp16 compute, fp32 MFMA accumulation; fp32 in/out (runtime-verified).
// R8: fix R7's vt/lin_kv aliasing self-race in k_dwconv_t (vt moved to the
//     free former-conv_v slot). Keeps R7's: 64x128 GEMM tile for attn@v /
//     q-proj / out-proj (1024 blocks), fused dwconv_v+transpose, merged
//     probe + dwconv launches. 12 dispatches total.
// ---------------------------------------------------------------------------

#define GLOBAL_AS __attribute__((address_space(1)))
#define LDS_AS    __attribute__((address_space(3)))

typedef _Float16 h8 __attribute__((ext_vector_type(8)));
typedef float    f4_t __attribute__((ext_vector_type(4)));
typedef unsigned short us8 __attribute__((ext_vector_type(8)));

__device__ __forceinline__ float bf2f(unsigned short u) {
    union { unsigned int i; float f; } x; x.i = ((unsigned int)u) << 16; return x.f;
}
__device__ __forceinline__ float rd(const void* p, long i, int isBf) {
    return isBf ? bf2f(((const unsigned short*)p)[i]) : ((const float*)p)[i];
}

// ---------------------------------------------------------------------------
// Probes: blocks 0..15 = dtype sniff per tensor; block 16 = mask width.
struct Probe16 { const unsigned short* p[16]; int n[16]; };

__global__ void k_probes(Probe16 a, const unsigned int* __restrict__ mask,
                         int* __restrict__ flags) {
    if (blockIdx.x < 16) {
        __shared__ int cnt;
        if (threadIdx.x == 0) cnt = 0;
        __syncthreads();
        const unsigned short* s = a.p[blockIdx.x];
        const int n = a.n[blockIdx.x];
        int bad = 0;
        for (int i = threadIdx.x; i < n; i += 256) {
            int e = (s[i] >> 7) & 0xFF;
            if (e >= 0x8F || (e > 0 && e <= 0x60)) bad++;
        }
        atomicAdd(&cnt, bad);
        __syncthreads();
        if (threadIdx.x == 0) flags[blockIdx.x] = (cnt * 4 > n) ? 0 : 1;
    } else {
        __shared__ int vi32, vf32, vbf, vf16;
        if (threadIdx.x == 0) { vi32 = vf32 = vbf = vf16 = 0; }
        __syncthreads();
        int bi32 = 0, bf32 = 0, bbf = 0, bf16c = 0;
        for (int i = threadIdx.x; i < 4096; i += 256) {
            unsigned int w = mask[i];
            if (!(w == 0u || w == 1u)) bi32++;
            if (!(w == 0u || w == 0x3F800000u)) bf32++;
            unsigned int h0 = w & 0xFFFFu, h1 = w >> 16;
            if (!((h0 == 0u || h0 == 0x3F80u) && (h1 == 0u || h1 == 0x3F80u))) bbf++;
            if (!((h0 == 0u || h0 == 0x3C00u) && (h1 == 0u || h1 == 0x3C00u))) bf16c++;
        }
        if (bi32) atomicAdd(&vi32, 1);
        if (bf32) atomicAdd(&vf32, 1);
        if (bbf)  atomicAdd(&vbf, 1);
        if (bf16c) atomicAdd(&vf16, 1);
        __syncthreads();
        if (threadIdx.x == 0) {
            int w;
            if (vi32 == 0) w = 4;
            else if (vf32 == 0) w = 4;
            else if (vbf == 0) w = 2;
            else if (vf16 == 0) w = 2;
            else w = 1;
            flags[16] = w;
        }
    }
}

// Pack mask (any width) to bytes: out[i] = (elem[i] != 0). 4 elems/thread.
__global__ void k_mask_bytes(const void* __restrict__ m, unsigned char* __restrict__ out,
                             long n, const int* __restrict__ widthFlag) {
    long i = ((long)blockIdx.x * 256 + threadIdx.x) * 4;
    if (i >= n) return;
    const int w = *widthFlag;
    unsigned int packed = 0;
    if (w == 4) {
        const unsigned int* p = (const unsigned int*)m;
#pragma unroll
        for (int u = 0; u < 4; ++u) packed |= (p[i + u] != 0u ? 1u : 0u) << (8 * u);
    } else if (w == 2) {
        const unsigned short* p = (const unsigned short*)m;
#pragma unroll
        for (int u = 0; u < 4; ++u) packed |= (p[i + u] != 0u ? 1u : 0u) << (8 * u);
    } else {
        const unsigned char* p = (const unsigned char*)m;
#pragma unroll
        for (int u = 0; u < 4; ++u) packed |= (p[i + u] != 0u ? 1u : 0u) << (8 * u);
    }
    *(unsigned int*)(out + i) = packed;
}

// ---------------------------------------------------------------------------
__device__ __forceinline__ h8 cvt8(const void* src, size_t off8, int isBf) {
    h8 d;
    if (isBf) {
        us8 s = *(const us8*)((const unsigned short*)src + off8 * 8);
#pragma unroll
        for (int u = 0; u < 8; ++u) d[u] = (_Float16)bf2f(s[u]);
    } else {
        const float* f = (const float*)src + off8 * 8;
        f4_t a = *(const f4_t*)f;
        f4_t b = *(const f4_t*)(f + 4);
#pragma unroll
        for (int u = 0; u < 4; ++u) { d[u] = (_Float16)a[u]; d[4 + u] = (_Float16)b[u]; }
    }
    return d;
}

__global__ void k_h_to_f16(const void* __restrict__ s0, const void* __restrict__ s1,
                           _Float16* __restrict__ dst, int n8each,
                           const int* __restrict__ flags) {
    int i = blockIdx.x * blockDim.x + threadIdx.x;
    if (i >= 2 * n8each) return;
    int seg = i / n8each, off = i - seg * n8each;
    h8 d = cvt8(seg ? s1 : s0, off, flags[seg]);
    *(h8*)(dst + (size_t)i * 8) = d;
}

struct Ptr4 { const void* p[4]; };
__global__ void k_w_to_f16(Ptr4 srcs, _Float16* __restrict__ dst, int n8each,
                           const int* __restrict__ flags) {
    int i = blockIdx.x * blockDim.x + threadIdx.x;
    if (i >= 4 * n8each) return;
    int seg = i / n8each, off = i - seg * n8each;
    h8 d = cvt8(srcs.p[seg], off, flags[seg]);
    *(h8*)(dst + (size_t)i * 8) = d;
}

// ---------------------------------------------------------------------------
// NT GEMM, MTILE x 128 x 32 tiles (MTILE = 128 or 64), 4 waves/block.
// MTILE=128: waves 2x2 of 64x64 (acc 4x4). MTILE=64: waves 2x2 of 32x64
// (acc 2x4, 3 global_load_lds/thread) -> 2x the blocks for small grids.
// XCD-aware 1D decode; LDS chunk swizzle (2-way conflicts = free).
// MODE 0: fp16 out            MODE 1: fp16 out + bias (bias2 = 2nd N-half)
// MODE 2: fp32 out + bias     MODE 3: fp16 scores (scale + byte-mask)
template <int MODE, int MTILE>
__global__ __launch_bounds__(256) void k_gemm_nt(
    const _Float16* __restrict__ A, const _Float16* __restrict__ Bm,
    void* __restrict__ Cout,
    const void* __restrict__ bias, const int* __restrict__ biasFlag,
    const void* __restrict__ bias2, const int* __restrict__ biasFlag2,
    int N, int K, long sA, long sB, long sC,
    float scale, const unsigned char* __restrict__ mask8,
    int NT, int BZ) {

    constexpr int NI = (MTILE == 128) ? 4 : 2;
    __shared__ __align__(16) _Float16 As[MTILE * 32];
    __shared__ __align__(16) _Float16 Bs[128 * 32];

    // ---- XCD-aware block decode ----
    const long id = blockIdx.x;
    const int xcd = (int)(id & 7);
    const long local = id >> 3;
    const int col = (int)(local % NT);
    const long g = (local / NT) * 8 + xcd;
    const int bz = (int)(g % BZ);
    const int brow = (int)(g / BZ);

    const int tid  = threadIdx.x;
    const int wave = tid >> 6, lane = tid & 63;
    const int wm = (wave >> 1) * (MTILE / 2), wn = (wave & 1) * 64;
    const int lr = lane & 15, lq = lane >> 4;

    const _Float16* Ab = A + (long)bz * sA + (size_t)brow * MTILE * K;
    const _Float16* Bb = Bm + (long)bz * sB + (size_t)col * 128 * K;

    f4_t acc[NI][4] = {};

    // staging: LDS slot c holds global (row=c>>2, seg=((c&3)-(c>>3))&3)
    const int c1 = tid, c2 = tid + 256;
    const int r1 = c1 >> 2, s1 = ((c1 & 3) - (c1 >> 3)) & 3;
    const int r2 = c2 >> 2, s2 = ((c2 & 3) - (c2 >> 3)) & 3;
    const _Float16* gA1 = Ab + (size_t)r1 * K + s1 * 8;
    const _Float16* gA2 = Ab + (size_t)r2 * K + s2 * 8;   // MTILE==128 only
    const _Float16* gB1 = Bb + (size_t)r1 * K + s1 * 8;
    const _Float16* gB2 = Bb + (size_t)r2 * K + s2 * 8;
    _Float16* lA1 = As + c1 * 8; _Float16* lA2 = As + c2 * 8;
    _Float16* lB1 = Bs + c1 * 8; _Float16* lB2 = Bs + c2 * 8;

    const int fseg = ((lq + (lr >> 1)) & 3) * 8;

    for (int kb = 0; kb < K; kb += 32) {
        __builtin_amdgcn_global_load_lds((void GLOBAL_AS*)(gA1 + kb), (void LDS_AS*)lA1, 16, 0, 0);
        if constexpr (MTILE == 128)
            __builtin_amdgcn_global_load_lds((void GLOBAL_AS*)(gA2 + kb), (void LDS_AS*)lA2, 16, 0, 0);
        __builtin_amdgcn_global_load_lds((void GLOBAL_AS*)(gB1 + kb), (void LDS_AS*)lB1, 16, 0, 0);
        __builtin_amdgcn_global_load_lds((void GLOBAL_AS*)(gB2 + kb), (void LDS_AS*)lB2, 16, 0, 0);
        __syncthreads();

        h8 af[NI], bfr[4];
#pragma unroll
        for (int i = 0; i < NI; ++i) af[i]  = *(const h8*)&As[(wm + i * 16 + lr) * 32 + fseg];
#pragma unroll
        for (int j = 0; j < 4; ++j) bfr[j] = *(const h8*)&Bs[(wn + j * 16 + lr) * 32 + fseg];
#pragma unroll
        for (int i = 0; i < NI; ++i)
#pragma unroll
            for (int j = 0; j < 4; ++j)
                acc[i][j] = __builtin_amdgcn_mfma_f32_16x16x32_f16(af[i], bfr[j], acc[i][j], 0, 0, 0);
        __syncthreads();
    }

    // epilogue: C/D layout col=lane&15, row=(lane>>4)*4+reg
    const long row0 = (long)brow * MTILE + wm + lq * 4;
    const long col0 = (long)col * 128 + wn + lr;

    if constexpr (MODE == 3) {
        _Float16* C = (_Float16*)Cout + (long)bz * sC;
#pragma unroll
        for (int i = 0; i < NI; ++i)
#pragma unroll
            for (int j = 0; j < 4; ++j)
#pragma unroll
                for (int r = 0; r < 4; ++r) {
                    long row = row0 + i * 16 + r;
                    long ccol = col0 + j * 16;
                    bool keep = mask8[row * (long)N + ccol] != 0;
                    float v = acc[i][j][r] * scale;
                    v = fminf(fmaxf(v, -60000.0f), 60000.0f);
                    C[row * (long)N + ccol] = (_Float16)(keep ? v : -60000.0f);
                }
    } else {
        float bv[4];
        if constexpr (MODE != 0) {
            const void* bp = bias; const int* bfp = biasFlag; long boff = 0;
            if (bias2 != nullptr && col * 128 >= (N >> 1)) {
                bp = bias2; bfp = biasFlag2; boff = (long)(N >> 1);
            }
            const int bIs = *bfp;
#pragma unroll
            for (int j = 0; j < 4; ++j) bv[j] = rd(bp, col0 + j * 16 - boff, bIs);
        } else {
#pragma unroll
            for (int j = 0; j < 4; ++j) bv[j] = 0.0f;
        }
        if constexpr (MODE == 2) {
            float* C = (float*)Cout + (long)bz * sC;
#pragma unroll
            for (int i = 0; i < NI; ++i)
#pragma unroll
                for (int j = 0; j < 4; ++j)
#pragma unroll
                    for (int r = 0; r < 4; ++r)
                        C[(row0 + i * 16 + r) * (long)N + col0 + j * 16] = acc[i][j][r] + bv[j];
        } else {
            _Float16* C = (_Float16*)Cout + (long)bz * sC;
#pragma unroll
            for (int i = 0; i < NI; ++i)
#pragma unroll
                for (int j = 0; j < 4; ++j)
#pragma unroll
                    for (int r = 0; r < 4; ++r) {
                        float v = acc[i][j][r] + bv[j];
                        v = fminf(fmaxf(v, -65000.0f), 65000.0f);
                        C[(row0 + i * 16 + r) * (long)N + col0 + j * 16] = (_Float16)v;
                    }
        }
    }
}

// ---------------------------------------------------------------------------
// Gated depthwise conv for q and k in one launch (z selects param set).
struct ConvP {
    const _Float16* x; int xs; _Float16* y;
    const void* kern; const void* cbias; const void* gate;
    const int* kF; const int* cbF;
};
__global__ void k_dwconv2(ConvP p0, ConvP p1, int S, int D) {
    const ConvP& p = blockIdx.z ? p1 : p0;
    int s = blockIdx.x, b = blockIdx.y;
    int d0 = threadIdx.x * 8;
    const size_t xb = ((size_t)b * S + s) * p.xs + d0;
    const size_t yb = ((size_t)b * S + s) * D + d0;
    const int kIs = *p.kF, cIs = *p.cbF;
    h8 zero;
#pragma unroll
    for (int u = 0; u < 8; ++u) zero[u] = (_Float16)0.0f;
    h8 xc = *(const h8*)(p.x + xb);
    h8 xp = (s > 0)     ? *(const h8*)(p.x + xb - p.xs) : zero;
    h8 xn = (s < S - 1) ? *(const h8*)(p.x + xb + p.xs) : zero;
    float tg = tanhf(rd(p.gate, 0, ((const unsigned int*)p.gate)[0] == 0u ? 1 : 0));
    h8 o;
#pragma unroll
    for (int u = 0; u < 8; ++u) {
        int d = d0 + u;
        float cv = (float)xp[u] * rd(p.kern, d * 3 + 0, kIs) +
                   (float)xc[u] * rd(p.kern, d * 3 + 1, kIs) +
                   (float)xn[u] * rd(p.kern, d * 3 + 2, kIs) + rd(p.cbias, d, cIs);
        float v = (float)xc[u] + tg * cv;
        o[u] = (_Float16)fminf(fmaxf(v, -65000.0f), 65000.0f);
    }
    *(h8*)(p.y + yb) = o;
}

// ---------------------------------------------------------------------------
// Fused dwconv_v + transpose: x = lin_kv+D (stride 2D), y = vt [B,D,SK].
// vt MUST NOT alias lin_kv (R7 bug): reads of x and writes of vt overlap in
// dispatch lifetime.
__global__ void k_dwconv_t(const _Float16* __restrict__ x, int xs,
                           _Float16* __restrict__ vt,
                           const void* __restrict__ kern,
                           const void* __restrict__ cbias,
                           const void* __restrict__ gate,
                           const int* __restrict__ kFlag, const int* __restrict__ cbFlag,
                           int SK, int D) {
    __shared__ _Float16 T[64][65];
    int b = blockIdx.z;
    int s0 = blockIdx.x * 64, d0 = blockIdx.y * 64;
    int tid = threadIdx.x;
    const int kIs = *kFlag, cIs = *cbFlag;
    float tg = tanhf(rd(gate, 0, ((const unsigned int*)gate)[0] == 0u ? 1 : 0));
    h8 zero;
#pragma unroll
    for (int u = 0; u < 8; ++u) zero[u] = (_Float16)0.0f;
#pragma unroll
    for (int it = 0; it < 2; ++it) {
        int idx = it * 256 + tid;
        int r = idx >> 3, c = (idx & 7) * 8;
        int s = s0 + r;
        const size_t xb = ((size_t)b * SK + s) * xs + d0 + c;
        h8 xc = *(const h8*)(x + xb);
        h8 xp = (s > 0)      ? *(const h8*)(x + xb - xs) : zero;
        h8 xn = (s < SK - 1) ? *(const h8*)(x + xb + xs) : zero;
#pragma unroll
        for (int u = 0; u < 8; ++u) {
            int d = d0 + c + u;
            float cv = (float)xp[u] * rd(kern, d * 3 + 0, kIs) +
                       (float)xc[u] * rd(kern, d * 3 + 1, kIs) +
                       (float)xn[u] * rd(kern, d * 3 + 2, kIs) + rd(cbias, d, cIs);
            float v = (float)xc[u] + tg * cv;
            T[r][c + u] = (_Float16)fminf(fmaxf(v, -65000.0f), 65000.0f);
        }
    }
    __syncthreads();
#pragma unroll
    for (int it = 0; it < 2; ++it) {
        int idx = it * 256 + tid;
        int dr = idx >> 3, c = (idx & 7) * 8;
        h8 o;
#pragma unroll
        for (int u = 0; u < 8; ++u) o[u] = T[c + u][dr];
        *(h8*)(vt + ((size_t)b * D + d0 + dr) * SK + s0 + c) = o;
    }
}

// ---------------------------------------------------------------------------
// Row softmax over SK=2048 fp16 scores; one 256-thread block per row.
__global__ __launch_bounds__(256) void k_softmax(const _Float16* __restrict__ sc,
                                                 _Float16* __restrict__ pr, int SK) {
    const long row = blockIdx.x;
    const int tid = threadIdx.x, lane = tid & 63, wave = tid >> 6;
    h8 v = *(const h8*)(sc + row * (long)SK + tid * 8);
    float f[8]; float mx = -3.0e38f;
#pragma unroll
    for (int u = 0; u < 8; ++u) { f[u] = (float)v[u]; mx = fmaxf(mx, f[u]); }
#pragma unroll
    for (int o = 32; o > 0; o >>= 1) mx = fmaxf(mx, __shfl_xor(mx, o, 64));
    __shared__ float red[8];
    if (lane == 0) red[wave] = mx;
    __syncthreads();
    mx = fmaxf(fmaxf(red[0], red[1]), fmaxf(red[2], red[3]));
    float sum = 0.0f;
#pragma unroll
    for (int u = 0; u < 8; ++u) { f[u] = __expf(f[u] - mx); sum += f[u]; }
#pragma unroll
    for (int o = 32; o > 0; o >>= 1) sum += __shfl_xor(sum, o, 64);
    if (lane == 0) red[4 + wave] = sum;
    __syncthreads();
    sum = red[4] + red[5] + red[6] + red[7];
    float inv = 1.0f / sum;
    h8 o8;
#pragma unroll
    for (int u = 0; u < 8; ++u) o8[u] = (_Float16)(f[u] * inv);
    *(h8*)(pr + row * (long)SK + tid * 8) = o8;
}

// ---------------------------------------------------------------------------
extern "C" void kernel_launch(void* const* d_in, const int* in_sizes, int n_in,
                              void* d_out, int out_size, void* d_ws, size_t ws_size,
                              hipStream_t stream) {
    const int Bn = 4, SQ = 2048, SK = 2048, D = 1024;
    const size_t nQ = (size_t)Bn * SQ * D;   // 8,388,608
    const long   nM = (long)SQ * SK;         // 4,194,304 mask elements

    const void* qh = d_in[0];
    const void* mh = d_in[1];
    const void* mask = d_in[2];
    const void* q_w = d_in[3];
    const void* q_b = d_in[4];
    const void* k_w = d_in[5];
    const void* k_b = d_in[6];
    const void* v_w = d_in[7];
    const void* v_b = d_in[8];
    const void* o_w = d_in[9];
    const void* o_b = d_in[10];
    const void* q_kern = d_in[11];
    const void* q_cb   = d_in[12];
    const void* q_g    = d_in[13];
    const void* k_kern = d_in[14];
    const void* k_cb   = d_in[15];
    const void* k_g    = d_in[16];
    const void* v_kern = d_in[17];
    const void* v_cb   = d_in[18];
    const void* v_g    = d_in[19];

    // ---- workspace layout (lifetime-overlaid) ----
    // [0,33.5MB)        scores -> attn_out
    // [33.5,41.9MB)     w16 x4 slots; mask8 overlays slots 0-1 after projections
    // [41.9,92.3MB)     lin_q + lin_kv; probs overlays [41.9,75.5MB) after convs
    // [92.3,125.8MB)    qh16/mh16 staging -> conv_q, conv_k
    // [125.8,142.6MB)   vt  (former conv_v slot -- must NOT alias lin_kv!)
    // [142.6MB+)        flags
    char* ws = (char*)d_ws;
    _Float16* scores   = (_Float16*)(ws + 0);
    _Float16* attn_out = (_Float16*)(ws + 0);
    _Float16* w16      = (_Float16*)(ws + 33554432);
    unsigned char* mask8 = (unsigned char*)(ws + 33554432);
    _Float16* lin      = (_Float16*)(ws + 41943040);
    _Float16* lin_q    = lin;
    _Float16* lin_kv   = lin + nQ;
    _Float16* probs    = lin;
    _Float16* conv     = (_Float16*)(ws + 92274688);
    _Float16* qh16     = conv;
    _Float16* mh16     = conv + nQ;
    _Float16* vt       = (_Float16*)(ws + 125829120);   // R8: moved off lin_kv
    int*      flags    = (int*)(ws + 142606336);

    // 0. probes (merged)
    Probe16 pa;
    const void* pp[16] = {qh, mh, q_w, k_w, v_w, o_w, q_kern, k_kern, v_kern,
                          q_b, k_b, v_b, o_b, q_cb, k_cb, v_cb};
    const int   pn[16] = {2048, 2048, 2048, 2048, 2048, 2048, 3072, 3072, 3072,
                          1024, 1024, 1024, 1024, 1024, 1024, 1024};
    for (int i = 0; i < 16; ++i) { pa.p[i] = (const unsigned short*)pp[i]; pa.n[i] = pn[i]; }
    k_probes<<<17, 256, 0, stream>>>(pa, (const unsigned int*)mask, flags);

    // 1. converts -> fp16
    const int nH8 = (int)(nQ / 8);
    k_h_to_f16<<<(2 * nH8 + 255) / 256, 256, 0, stream>>>(qh, mh, qh16, nH8, flags + 0);
    const int nW8 = D * D / 8;
    Ptr4 wp; wp.p[0] = q_w; wp.p[1] = k_w; wp.p[2] = v_w; wp.p[3] = o_w;
    k_w_to_f16<<<(4 * nW8 + 255) / 256, 256, 0, stream>>>(wp, w16, nW8, flags + 2);

    // 2. projections
    //    q: M=8192(64-tiles:128), N=1024 (NT=8), BZ=1 -> 1024 blocks
    k_gemm_nt<1, 64><<<dim3(1024), 256, 0, stream>>>(
        qh16, w16, lin_q, q_b, flags + 9, nullptr, nullptr,
        D, D, 0, 0, 0, 1.0f, nullptr, 8, 1);
    //    kv fused: M=8192(128-tiles:64), N=2048 (NT=16), BZ=1 -> 1024 blocks
    k_gemm_nt<1, 128><<<dim3(1024), 256, 0, stream>>>(
        mh16, w16 + (size_t)D * D, lin_kv, k_b, flags + 10, v_b, flags + 11,
        2 * D, D, 0, 0, 0, 1.0f, nullptr, 16, 1);

    // 2b. pack mask to bytes into the now-dead q/k weight slots
    k_mask_bytes<<<(int)(nM / 4 / 256), 256, 0, stream>>>(mask, mask8, nM, flags + 16);

    // 3. gated depthwise conv: q + k in one launch; v fused with transpose
    ConvP cq{lin_q, D, conv + 0 * nQ, q_kern, q_cb, q_g, flags + 6, flags + 13};
    ConvP ck{lin_kv, 2 * D, conv + 1 * nQ, k_kern, k_cb, k_g, flags + 7, flags + 14};
    k_dwconv2<<<dim3(SQ, Bn, 2), 128, 0, stream>>>(cq, ck, SQ, D);
    k_dwconv_t<<<dim3(SK / 64, D / 64, Bn), 256, 0, stream>>>(
        lin_kv + D, 2 * D, vt, v_kern, v_cb, v_g, flags + 8, flags + 15, SK, D);

    // 5. scores: per-batch M=2048(128:16), N=2048 (NT=16), BZ=4 -> 1024 blocks
    k_gemm_nt<3, 128><<<dim3(1024), 256, 0, stream>>>(
        conv + 0 * nQ, conv + 1 * nQ, scores, nullptr, nullptr, nullptr, nullptr,
        SK, D, (long)SQ * D, (long)SK * D, (long)SQ * SK, 0.03125f, mask8, 16, 4);

    // 6. softmax
    k_softmax<<<Bn * SQ, 256, 0, stream>>>(scores, probs, SK);

    // 7. attn @ v: per-batch M=2048(64:32), N=1024 (NT=8), BZ=4 -> 1024 blocks
    k_gemm_nt<0, 64><<<dim3(1024), 256, 0, stream>>>(
        probs, vt, attn_out, nullptr, nullptr, nullptr, nullptr,
        D, SK, (long)SQ * SK, (long)D * SK, (long)SQ * D, 1.0f, nullptr, 8, 4);

    // 8. out-proj: M=8192(64:128), N=1024 (NT=8), BZ=1 -> 1024 blocks, fp32 out
    k_gemm_nt<2, 64><<<dim3(1024), 256, 0, stream>>>(
        attn_out, w16 + 3 * (size_t)D * D, d_out, o_b, flags + 12, nullptr, nullptr,
        D, D, 0, 0, 0, 1.0f, nullptr, 8, 1);

    (void)in_sizes; (void)n_in; (void)out_size; (void)ws_size;
}

// Round 9
// 449.325 us; speedup vs baseline: 1.4943x; 1.2311x over previous
//
#include <hip/hip_runtime.h>
#include <cstdint>
#include <cstddef>

// ---------------------------------------------------------------------------
// TransformConvCrossAttention: B=4, SQ=SK=2048, D=1024, Kconv=3
// fp16 compute, fp32 MFMA accumulation; fp32 in/out (runtime-verified).
// R9: planar fp16 conv params (one-block precompute into dead v_w16 slot).
//     R8's dwconv kernels were L1-transaction-bound on scattered kern reads
//     (25 stride-96B dword loads/thread); now 4 coalesced h8 loads.
// ---------------------------------------------------------------------------

#define GLOBAL_AS __attribute__((address_space(1)))
#define LDS_AS    __attribute__((address_space(3)))

typedef _Float16 h8 __attribute__((ext_vector_type(8)));
typedef float    f4_t __attribute__((ext_vector_type(4)));
typedef unsigned short us8 __attribute__((ext_vector_type(8)));

__device__ __forceinline__ float bf2f(unsigned short u) {
    union { unsigned int i; float f; } x; x.i = ((unsigned int)u) << 16; return x.f;
}
__device__ __forceinline__ float rd(const void* p, long i, int isBf) {
    return isBf ? bf2f(((const unsigned short*)p)[i]) : ((const float*)p)[i];
}

// ---------------------------------------------------------------------------
// Probes: blocks 0..15 = dtype sniff per tensor; block 16 = mask width.
struct Probe16 { const unsigned short* p[16]; int n[16]; };

__global__ void k_probes(Probe16 a, const unsigned int* __restrict__ mask,
                         int* __restrict__ flags) {
    if (blockIdx.x < 16) {
        __shared__ int cnt;
        if (threadIdx.x == 0) cnt = 0;
        __syncthreads();
        const unsigned short* s = a.p[blockIdx.x];
        const int n = a.n[blockIdx.x];
        int bad = 0;
        for (int i = threadIdx.x; i < n; i += 256) {
            int e = (s[i] >> 7) & 0xFF;
            if (e >= 0x8F || (e > 0 && e <= 0x60)) bad++;
        }
        atomicAdd(&cnt, bad);
        __syncthreads();
        if (threadIdx.x == 0) flags[blockIdx.x] = (cnt * 4 > n) ? 0 : 1;
    } else {
        __shared__ int vi32, vf32, vbf, vf16;
        if (threadIdx.x == 0) { vi32 = vf32 = vbf = vf16 = 0; }
        __syncthreads();
        int bi32 = 0, bf32 = 0, bbf = 0, bf16c = 0;
        for (int i = threadIdx.x; i < 4096; i += 256) {
            unsigned int w = mask[i];
            if (!(w == 0u || w == 1u)) bi32++;
            if (!(w == 0u || w == 0x3F800000u)) bf32++;
            unsigned int h0 = w & 0xFFFFu, h1 = w >> 16;
            if (!((h0 == 0u || h0 == 0x3F80u) && (h1 == 0u || h1 == 0x3F80u))) bbf++;
            if (!((h0 == 0u || h0 == 0x3C00u) && (h1 == 0u || h1 == 0x3C00u))) bf16c++;
        }
        if (bi32) atomicAdd(&vi32, 1);
        if (bf32) atomicAdd(&vf32, 1);
        if (bbf)  atomicAdd(&vbf, 1);
        if (bf16c) atomicAdd(&vf16, 1);
        __syncthreads();
        if (threadIdx.x == 0) {
            int w;
            if (vi32 == 0) w = 4;
            else if (vf32 == 0) w = 4;
            else if (vbf == 0) w = 2;
            else if (vf16 == 0) w = 2;
            else w = 1;
            flags[16] = w;
        }
    }
}

// Pack mask (any width) to bytes: out[i] = (elem[i] != 0). 4 elems/thread.
__global__ void k_mask_bytes(const void* __restrict__ m, unsigned char* __restrict__ out,
                             long n, const int* __restrict__ widthFlag) {
    long i = ((long)blockIdx.x * 256 + threadIdx.x) * 4;
    if (i >= n) return;
    const int w = *widthFlag;
    unsigned int packed = 0;
    if (w == 4) {
        const unsigned int* p = (const unsigned int*)m;
#pragma unroll
        for (int u = 0; u < 4; ++u) packed |= (p[i + u] != 0u ? 1u : 0u) << (8 * u);
    } else if (w == 2) {
        const unsigned short* p = (const unsigned short*)m;
#pragma unroll
        for (int u = 0; u < 4; ++u) packed |= (p[i + u] != 0u ? 1u : 0u) << (8 * u);
    } else {
        const unsigned char* p = (const unsigned char*)m;
#pragma unroll
        for (int u = 0; u < 4; ++u) packed |= (p[i + u] != 0u ? 1u : 0u) << (8 * u);
    }
    *(unsigned int*)(out + i) = packed;
}

// ---------------------------------------------------------------------------
// Conv param precompute: kern [D,3] (dtype-flagged) -> planar fp16 [3][D];
// cbias -> fp16 [D]; tanh(gate) -> float. One block, 256 threads.
// Layout at `out`: t*3*D + j*D + d (kern), 9*D + t*D + d (cbias); tg[3] floats.
struct ConvSrc { const void* kern[3]; const void* cb[3]; const void* gate[3]; };
__global__ void k_conv_params(ConvSrc p, const int* __restrict__ flags,
                              _Float16* __restrict__ out, float* __restrict__ tg, int D) {
#pragma unroll
    for (int t = 0; t < 3; ++t) {
        const int kIs = flags[6 + t], cIs = flags[13 + t];
        for (int d = threadIdx.x; d < D; d += 256) {
#pragma unroll
            for (int j = 0; j < 3; ++j)
                out[t * 3 * D + j * D + d] = (_Float16)rd(p.kern[t], (long)d * 3 + j, kIs);
            out[9 * D + t * D + d] = (_Float16)rd(p.cb[t], d, cIs);
        }
    }
    if (threadIdx.x < 3) {
        const void* g = p.gate[threadIdx.x];
        float gv = rd(g, 0, ((const unsigned int*)g)[0] == 0u ? 1 : 0);
        tg[threadIdx.x] = tanhf(gv);
    }
}

// ---------------------------------------------------------------------------
__device__ __forceinline__ h8 cvt8(const void* src, size_t off8, int isBf) {
    h8 d;
    if (isBf) {
        us8 s = *(const us8*)((const unsigned short*)src + off8 * 8);
#pragma unroll
        for (int u = 0; u < 8; ++u) d[u] = (_Float16)bf2f(s[u]);
    } else {
        const float* f = (const float*)src + off8 * 8;
        f4_t a = *(const f4_t*)f;
        f4_t b = *(const f4_t*)(f + 4);
#pragma unroll
        for (int u = 0; u < 4; ++u) { d[u] = (_Float16)a[u]; d[4 + u] = (_Float16)b[u]; }
    }
    return d;
}

__global__ void k_h_to_f16(const void* __restrict__ s0, const void* __restrict__ s1,
                           _Float16* __restrict__ dst, int n8each,
                           const int* __restrict__ flags) {
    int i = blockIdx.x * blockDim.x + threadIdx.x;
    if (i >= 2 * n8each) return;
    int seg = i / n8each, off = i - seg * n8each;
    h8 d = cvt8(seg ? s1 : s0, off, flags[seg]);
    *(h8*)(dst + (size_t)i * 8) = d;
}

struct Ptr4 { const void* p[4]; };
__global__ void k_w_to_f16(Ptr4 srcs, _Float16* __restrict__ dst, int n8each,
                           const int* __restrict__ flags) {
    int i = blockIdx.x * blockDim.x + threadIdx.x;
    if (i >= 4 * n8each) return;
    int seg = i / n8each, off = i - seg * n8each;
    h8 d = cvt8(srcs.p[seg], off, flags[seg]);
    *(h8*)(dst + (size_t)i * 8) = d;
}

// ---------------------------------------------------------------------------
// NT GEMM, MTILE x 128 x 32 tiles (MTILE = 128 or 64), 4 waves/block.
// XCD-aware 1D decode; LDS chunk swizzle (2-way conflicts = free).
// MODE 0: fp16 out            MODE 1: fp16 out + bias (bias2 = 2nd N-half)
// MODE 2: fp32 out + bias     MODE 3: fp16 scores (scale + byte-mask)
template <int MODE, int MTILE>
__global__ __launch_bounds__(256) void k_gemm_nt(
    const _Float16* __restrict__ A, const _Float16* __restrict__ Bm,
    void* __restrict__ Cout,
    const void* __restrict__ bias, const int* __restrict__ biasFlag,
    const void* __restrict__ bias2, const int* __restrict__ biasFlag2,
    int N, int K, long sA, long sB, long sC,
    float scale, const unsigned char* __restrict__ mask8,
    int NT, int BZ) {

    constexpr int NI = (MTILE == 128) ? 4 : 2;
    __shared__ __align__(16) _Float16 As[MTILE * 32];
    __shared__ __align__(16) _Float16 Bs[128 * 32];

    const long id = blockIdx.x;
    const int xcd = (int)(id & 7);
    const long local = id >> 3;
    const int col = (int)(local % NT);
    const long g = (local / NT) * 8 + xcd;
    const int bz = (int)(g % BZ);
    const int brow = (int)(g / BZ);

    const int tid  = threadIdx.x;
    const int wave = tid >> 6, lane = tid & 63;
    const int wm = (wave >> 1) * (MTILE / 2), wn = (wave & 1) * 64;
    const int lr = lane & 15, lq = lane >> 4;

    const _Float16* Ab = A + (long)bz * sA + (size_t)brow * MTILE * K;
    const _Float16* Bb = Bm + (long)bz * sB + (size_t)col * 128 * K;

    f4_t acc[NI][4] = {};

    const int c1 = tid, c2 = tid + 256;
    const int r1 = c1 >> 2, s1 = ((c1 & 3) - (c1 >> 3)) & 3;
    const int r2 = c2 >> 2, s2 = ((c2 & 3) - (c2 >> 3)) & 3;
    const _Float16* gA1 = Ab + (size_t)r1 * K + s1 * 8;
    const _Float16* gA2 = Ab + (size_t)r2 * K + s2 * 8;   // MTILE==128 only
    const _Float16* gB1 = Bb + (size_t)r1 * K + s1 * 8;
    const _Float16* gB2 = Bb + (size_t)r2 * K + s2 * 8;
    _Float16* lA1 = As + c1 * 8; _Float16* lA2 = As + c2 * 8;
    _Float16* lB1 = Bs + c1 * 8; _Float16* lB2 = Bs + c2 * 8;

    const int fseg = ((lq + (lr >> 1)) & 3) * 8;

    for (int kb = 0; kb < K; kb += 32) {
        __builtin_amdgcn_global_load_lds((void GLOBAL_AS*)(gA1 + kb), (void LDS_AS*)lA1, 16, 0, 0);
        if constexpr (MTILE == 128)
            __builtin_amdgcn_global_load_lds((void GLOBAL_AS*)(gA2 + kb), (void LDS_AS*)lA2, 16, 0, 0);
        __builtin_amdgcn_global_load_lds((void GLOBAL_AS*)(gB1 + kb), (void LDS_AS*)lB1, 16, 0, 0);
        __builtin_amdgcn_global_load_lds((void GLOBAL_AS*)(gB2 + kb), (void LDS_AS*)lB2, 16, 0, 0);
        __syncthreads();

        h8 af[NI], bfr[4];
#pragma unroll
        for (int i = 0; i < NI; ++i) af[i]  = *(const h8*)&As[(wm + i * 16 + lr) * 32 + fseg];
#pragma unroll
        for (int j = 0; j < 4; ++j) bfr[j] = *(const h8*)&Bs[(wn + j * 16 + lr) * 32 + fseg];
#pragma unroll
        for (int i = 0; i < NI; ++i)
#pragma unroll
            for (int j = 0; j < 4; ++j)
                acc[i][j] = __builtin_amdgcn_mfma_f32_16x16x32_f16(af[i], bfr[j], acc[i][j], 0, 0, 0);
        __syncthreads();
    }

    const long row0 = (long)brow * MTILE + wm + lq * 4;
    const long col0 = (long)col * 128 + wn + lr;

    if constexpr (MODE == 3) {
        _Float16* C = (_Float16*)Cout + (long)bz * sC;
#pragma unroll
        for (int i = 0; i < NI; ++i)
#pragma unroll
            for (int j = 0; j < 4; ++j)
#pragma unroll
                for (int r = 0; r < 4; ++r) {
                    long row = row0 + i * 16 + r;
                    long ccol = col0 + j * 16;
                    bool keep = mask8[row * (long)N + ccol] != 0;
                    float v = acc[i][j][r] * scale;
                    v = fminf(fmaxf(v, -60000.0f), 60000.0f);
                    C[row * (long)N + ccol] = (_Float16)(keep ? v : -60000.0f);
                }
    } else {
        float bv[4];
        if constexpr (MODE != 0) {
            const void* bp = bias; const int* bfp = biasFlag; long boff = 0;
            if (bias2 != nullptr && col * 128 >= (N >> 1)) {
                bp = bias2; bfp = biasFlag2; boff = (long)(N >> 1);
            }
            const int bIs = *bfp;
#pragma unroll
            for (int j = 0; j < 4; ++j) bv[j] = rd(bp, col0 + j * 16 - boff, bIs);
        } else {
#pragma unroll
            for (int j = 0; j < 4; ++j) bv[j] = 0.0f;
        }
        if constexpr (MODE == 2) {
            float* C = (float*)Cout + (long)bz * sC;
#pragma unroll
            for (int i = 0; i < NI; ++i)
#pragma unroll
                for (int j = 0; j < 4; ++j)
#pragma unroll
                    for (int r = 0; r < 4; ++r)
                        C[(row0 + i * 16 + r) * (long)N + col0 + j * 16] = acc[i][j][r] + bv[j];
        } else {
            _Float16* C = (_Float16*)Cout + (long)bz * sC;
#pragma unroll
            for (int i = 0; i < NI; ++i)
#pragma unroll
                for (int j = 0; j < 4; ++j)
#pragma unroll
                    for (int r = 0; r < 4; ++r) {
                        float v = acc[i][j][r] + bv[j];
                        v = fminf(fmaxf(v, -65000.0f), 65000.0f);
                        C[(row0 + i * 16 + r) * (long)N + col0 + j * 16] = (_Float16)v;
                    }
        }
    }
}

// ---------------------------------------------------------------------------
// Gated depthwise conv for q and k in one launch (z selects param set).
// Params are planar fp16 (kp[j*D+d], cb[d]) + precomputed tanh(gate).
struct ConvP {
    const _Float16* x; int xs; _Float16* y;
    const _Float16* kp; const _Float16* cb; const float* tg;
};
__global__ void k_dwconv2(ConvP p0, ConvP p1, int S, int D) {
    const ConvP& p = blockIdx.z ? p1 : p0;
    int s = blockIdx.x, b = blockIdx.y;
    int d0 = threadIdx.x * 8;
    const size_t xb = ((size_t)b * S + s) * p.xs + d0;
    const size_t yb = ((size_t)b * S + s) * D + d0;
    h8 zero;
#pragma unroll
    for (int u = 0; u < 8; ++u) zero[u] = (_Float16)0.0f;
    h8 xc = *(const h8*)(p.x + xb);
    h8 xp = (s > 0)     ? *(const h8*)(p.x + xb - p.xs) : zero;
    h8 xn = (s < S - 1) ? *(const h8*)(p.x + xb + p.xs) : zero;
    h8 k0 = *(const h8*)(p.kp + 0 * D + d0);
    h8 k1 = *(const h8*)(p.kp + 1 * D + d0);
    h8 k2 = *(const h8*)(p.kp + 2 * D + d0);
    h8 cb = *(const h8*)(p.cb + d0);
    float tg = *p.tg;
    h8 o;
#pragma unroll
    for (int u = 0; u < 8; ++u) {
        float cv = (float)xp[u] * (float)k0[u] + (float)xc[u] * (float)k1[u] +
                   (float)xn[u] * (float)k2[u] + (float)cb[u];
        float v = (float)xc[u] + tg * cv;
        o[u] = (_Float16)fminf(fmaxf(v, -65000.0f), 65000.0f);
    }
    *(h8*)(p.y + yb) = o;
}

// ---------------------------------------------------------------------------
// Fused dwconv_v + transpose: x = lin_kv+D (stride 2D), y = vt [B,D,SK].
// vt MUST NOT alias lin_kv (R7 bug). Planar fp16 params.
__global__ void k_dwconv_t(const _Float16* __restrict__ x, int xs,
                           _Float16* __restrict__ vt,
                           const _Float16* __restrict__ kp,
                           const _Float16* __restrict__ cbp,
                           const float* __restrict__ tgp,
                           int SK, int D) {
    __shared__ _Float16 T[64][65];
    int b = blockIdx.z;
    int s0 = blockIdx.x * 64, d0 = blockIdx.y * 64;
    int tid = threadIdx.x;
    float tg = *tgp;
    h8 zero;
#pragma unroll
    for (int u = 0; u < 8; ++u) zero[u] = (_Float16)0.0f;
#pragma unroll
    for (int it = 0; it < 2; ++it) {
        int idx = it * 256 + tid;
        int r = idx >> 3, c = (idx & 7) * 8;
        int s = s0 + r;
        const size_t xb = ((size_t)b * SK + s) * xs + d0 + c;
        h8 xc = *(const h8*)(x + xb);
        h8 xp = (s > 0)      ? *(const h8*)(x + xb - xs) : zero;
        h8 xn = (s < SK - 1) ? *(const h8*)(x + xb + xs) : zero;
        h8 k0 = *(const h8*)(kp + 0 * D + d0 + c);
        h8 k1 = *(const h8*)(kp + 1 * D + d0 + c);
        h8 k2 = *(const h8*)(kp + 2 * D + d0 + c);
        h8 cb = *(const h8*)(cbp + d0 + c);
#pragma unroll
        for (int u = 0; u < 8; ++u) {
            float cv = (float)xp[u] * (float)k0[u] + (float)xc[u] * (float)k1[u] +
                       (float)xn[u] * (float)k2[u] + (float)cb[u];
            float v = (float)xc[u] + tg * cv;
            T[r][c + u] = (_Float16)fminf(fmaxf(v, -65000.0f), 65000.0f);
        }
    }
    __syncthreads();
#pragma unroll
    for (int it = 0; it < 2; ++it) {
        int idx = it * 256 + tid;
        int dr = idx >> 3, c = (idx & 7) * 8;
        h8 o;
#pragma unroll
        for (int u = 0; u < 8; ++u) o[u] = T[c + u][dr];
        *(h8*)(vt + ((size_t)b * D + d0 + dr) * SK + s0 + c) = o;
    }
}

// ---------------------------------------------------------------------------
// Row softmax over SK=2048 fp16 scores; one 256-thread block per row.
__global__ __launch_bounds__(256) void k_softmax(const _Float16* __restrict__ sc,
                                                 _Float16* __restrict__ pr, int SK) {
    const long row = blockIdx.x;
    const int tid = threadIdx.x, lane = tid & 63, wave = tid >> 6;
    h8 v = *(const h8*)(sc + row * (long)SK + tid * 8);
    float f[8]; float mx = -3.0e38f;
#pragma unroll
    for (int u = 0; u < 8; ++u) { f[u] = (float)v[u]; mx = fmaxf(mx, f[u]); }
#pragma unroll
    for (int o = 32; o > 0; o >>= 1) mx = fmaxf(mx, __shfl_xor(mx, o, 64));
    __shared__ float red[8];
    if (lane == 0) red[wave] = mx;
    __syncthreads();
    mx = fmaxf(fmaxf(red[0], red[1]), fmaxf(red[2], red[3]));
    float sum = 0.0f;
#pragma unroll
    for (int u = 0; u < 8; ++u) { f[u] = __expf(f[u] - mx); sum += f[u]; }
#pragma unroll
    for (int o = 32; o > 0; o >>= 1) sum += __shfl_xor(sum, o, 64);
    if (lane == 0) red[4 + wave] = sum;
    __syncthreads();
    sum = red[4] + red[5] + red[6] + red[7];
    float inv = 1.0f / sum;
    h8 o8;
#pragma unroll
    for (int u = 0; u < 8; ++u) o8[u] = (_Float16)(f[u] * inv);
    *(h8*)(pr + row * (long)SK + tid * 8) = o8;
}

// ---------------------------------------------------------------------------
extern "C" void kernel_launch(void* const* d_in, const int* in_sizes, int n_in,
                              void* d_out, int out_size, void* d_ws, size_t ws_size,
                              hipStream_t stream) {
    const int Bn = 4, SQ = 2048, SK = 2048, D = 1024;
    const size_t nQ = (size_t)Bn * SQ * D;   // 8,388,608
    const long   nM = (long)SQ * SK;         // 4,194,304 mask elements

    const void* qh = d_in[0];
    const void* mh = d_in[1];
    const void* mask = d_in[2];
    const void* q_w = d_in[3];
    const void* q_b = d_in[4];
    const void* k_w = d_in[5];
    const void* k_b = d_in[6];
    const void* v_w = d_in[7];
    const void* v_b = d_in[8];
    const void* o_w = d_in[9];
    const void* o_b = d_in[10];
    const void* q_kern = d_in[11];
    const void* q_cb   = d_in[12];
    const void* q_g    = d_in[13];
    const void* k_kern = d_in[14];
    const void* k_cb   = d_in[15];
    const void* k_g    = d_in[16];
    const void* v_kern = d_in[17];
    const void* v_cb   = d_in[18];
    const void* v_g    = d_in[19];

    // ---- workspace layout (lifetime-overlaid) ----
    // [0,33.5MB)        scores -> attn_out
    // [33.5,41.9MB)     w16 x4 slots; after kv-proj: mask8 overlays slots 0-1,
    //                   conv params (planar fp16 + tg) overlay slot 2
    // [41.9,92.3MB)     lin_q + lin_kv; probs overlays [41.9,75.5MB) after convs
    // [92.3,125.8MB)    qh16/mh16 staging -> conv_q, conv_k
    // [125.8,142.6MB)   vt  (must NOT alias lin_kv)
    // [142.6MB+)        flags
    char* ws = (char*)d_ws;
    _Float16* scores   = (_Float16*)(ws + 0);
    _Float16* attn_out = (_Float16*)(ws + 0);
    _Float16* w16      = (_Float16*)(ws + 33554432);
    unsigned char* mask8 = (unsigned char*)(ws + 33554432);
    _Float16* par16    = (_Float16*)(ws + 37748736);     // dead v_w16 slot (2MB)
    float*    tgf      = (float*)(ws + 37748736 + 12 * 1024 * 2);
    _Float16* lin      = (_Float16*)(ws + 41943040);
    _Float16* lin_q    = lin;
    _Float16* lin_kv   = lin + nQ;
    _Float16* probs    = lin;
    _Float16* conv     = (_Float16*)(ws + 92274688);
    _Float16* qh16     = conv;
    _Float16* mh16     = conv + nQ;
    _Float16* vt       = (_Float16*)(ws + 125829120);
    int*      flags    = (int*)(ws + 142606336);

    // 0. probes (merged)
    Probe16 pa;
    const void* pp[16] = {qh, mh, q_w, k_w, v_w, o_w, q_kern, k_kern, v_kern,
                          q_b, k_b, v_b, o_b, q_cb, k_cb, v_cb};
    const int   pn[16] = {2048, 2048, 2048, 2048, 2048, 2048, 3072, 3072, 3072,
                          1024, 1024, 1024, 1024, 1024, 1024, 1024};
    for (int i = 0; i < 16; ++i) { pa.p[i] = (const unsigned short*)pp[i]; pa.n[i] = pn[i]; }
    k_probes<<<17, 256, 0, stream>>>(pa, (const unsigned int*)mask, flags);

    // 1. converts -> fp16
    const int nH8 = (int)(nQ / 8);
    k_h_to_f16<<<(2 * nH8 + 255) / 256, 256, 0, stream>>>(qh, mh, qh16, nH8, flags + 0);
    const int nW8 = D * D / 8;
    Ptr4 wp; wp.p[0] = q_w; wp.p[1] = k_w; wp.p[2] = v_w; wp.p[3] = o_w;
    k_w_to_f16<<<(4 * nW8 + 255) / 256, 256, 0, stream>>>(wp, w16, nW8, flags + 2);

    // 2. projections
    k_gemm_nt<1, 64><<<dim3(1024), 256, 0, stream>>>(
        qh16, w16, lin_q, q_b, flags + 9, nullptr, nullptr,
        D, D, 0, 0, 0, 1.0f, nullptr, 8, 1);
    k_gemm_nt<1, 128><<<dim3(1024), 256, 0, stream>>>(
        mh16, w16 + (size_t)D * D, lin_kv, k_b, flags + 10, v_b, flags + 11,
        2 * D, D, 0, 0, 0, 1.0f, nullptr, 16, 1);

    // 2b. pack mask + conv params into the now-dead w16 slots
    k_mask_bytes<<<(int)(nM / 4 / 256), 256, 0, stream>>>(mask, mask8, nM, flags + 16);
    ConvSrc cs;
    cs.kern[0] = q_kern; cs.kern[1] = k_kern; cs.kern[2] = v_kern;
    cs.cb[0] = q_cb; cs.cb[1] = k_cb; cs.cb[2] = v_cb;
    cs.gate[0] = q_g; cs.gate[1] = k_g; cs.gate[2] = v_g;
    k_conv_params<<<1, 256, 0, stream>>>(cs, flags, par16, tgf, D);

    // 3. gated depthwise conv: q + k in one launch; v fused with transpose
    ConvP cq{lin_q, D, conv + 0 * nQ, par16 + 0 * 3 * D, par16 + 9 * D + 0 * D, tgf + 0};
    ConvP ck{lin_kv, 2 * D, conv + 1 * nQ, par16 + 1 * 3 * D, par16 + 9 * D + 1 * D, tgf + 1};
    k_dwconv2<<<dim3(SQ, Bn, 2), 128, 0, stream>>>(cq, ck, SQ, D);
    k_dwconv_t<<<dim3(SK / 64, D / 64, Bn), 256, 0, stream>>>(
        lin_kv + D, 2 * D, vt, par16 + 2 * 3 * D, par16 + 9 * D + 2 * D, tgf + 2, SK, D);

    // 5. scores: per-batch M=2048(128:16), N=2048 (NT=16), BZ=4 -> 1024 blocks
    k_gemm_nt<3, 128><<<dim3(1024), 256, 0, stream>>>(
        conv + 0 * nQ, conv + 1 * nQ, scores, nullptr, nullptr, nullptr, nullptr,
        SK, D, (long)SQ * D, (long)SK * D, (long)SQ * SK, 0.03125f, mask8, 16, 4);

    // 6. softmax
    k_softmax<<<Bn * SQ, 256, 0, stream>>>(scores, probs, SK);

    // 7. attn @ v: per-batch M=2048(64:32), N=1024 (NT=8), BZ=4 -> 1024 blocks
    k_gemm_nt<0, 64><<<dim3(1024), 256, 0, stream>>>(
        probs, vt, attn_out, nullptr, nullptr, nullptr, nullptr,
        D, SK, (long)SQ * SK, (long)D * SK, (long)SQ * D, 1.0f, nullptr, 8, 4);

    // 8. out-proj: M=8192(64:128), N=1024 (NT=8), BZ=1 -> 1024 blocks, fp32 out
    k_gemm_nt<2, 64><<<dim3(1024), 256, 0, stream>>>(
        attn_out, w16 + 3 * (size_t)D * D, d_out, o_b, flags + 12, nullptr, nullptr,
        D, D, 0, 0, 0, 1.0f, nullptr, 8, 1);

    (void)in_sizes; (void)n_in; (void)out_size; (void)ws_size;
}

// Round 10
// 406.301 us; speedup vs baseline: 1.6526x; 1.1059x over previous
//
#include <hip/hip_runtime.h>
#include <cstdint>
#include <cstddef>

// ---------------------------------------------------------------------------
// TransformConvCrossAttention: B=4, SQ=SK=2048, D=1024, Kconv=3
// fp16 compute, fp32 MFMA accumulation; fp32 in/out (runtime-verified).
// R10: BK=64 K-loop for all GEMMs (half the barrier count vs BK=32,
//      occupancy-neutral: 32KB LDS, __launch_bounds__(256,4) caps VGPR<=128).
//      Swizzle generalized: physical seg p=(seg+row)&7 within 8-seg rows.
// ---------------------------------------------------------------------------

#define GLOBAL_AS __attribute__((address_space(1)))
#define LDS_AS    __attribute__((address_space(3)))

typedef _Float16 h8 __attribute__((ext_vector_type(8)));
typedef float    f4_t __attribute__((ext_vector_type(4)));
typedef unsigned short us8 __attribute__((ext_vector_type(8)));

__device__ __forceinline__ float bf2f(unsigned short u) {
    union { unsigned int i; float f; } x; x.i = ((unsigned int)u) << 16; return x.f;
}
__device__ __forceinline__ float rd(const void* p, long i, int isBf) {
    return isBf ? bf2f(((const unsigned short*)p)[i]) : ((const float*)p)[i];
}

// ---------------------------------------------------------------------------
// Probes: blocks 0..15 = dtype sniff per tensor; block 16 = mask width.
struct Probe16 { const unsigned short* p[16]; int n[16]; };

__global__ void k_probes(Probe16 a, const unsigned int* __restrict__ mask,
                         int* __restrict__ flags) {
    if (blockIdx.x < 16) {
        __shared__ int cnt;
        if (threadIdx.x == 0) cnt = 0;
        __syncthreads();
        const unsigned short* s = a.p[blockIdx.x];
        const int n = a.n[blockIdx.x];
        int bad = 0;
        for (int i = threadIdx.x; i < n; i += 256) {
            int e = (s[i] >> 7) & 0xFF;
            if (e >= 0x8F || (e > 0 && e <= 0x60)) bad++;
        }
        atomicAdd(&cnt, bad);
        __syncthreads();
        if (threadIdx.x == 0) flags[blockIdx.x] = (cnt * 4 > n) ? 0 : 1;
    } else {
        __shared__ int vi32, vf32, vbf, vf16;
        if (threadIdx.x == 0) { vi32 = vf32 = vbf = vf16 = 0; }
        __syncthreads();
        int bi32 = 0, bf32 = 0, bbf = 0, bf16c = 0;
        for (int i = threadIdx.x; i < 4096; i += 256) {
            unsigned int w = mask[i];
            if (!(w == 0u || w == 1u)) bi32++;
            if (!(w == 0u || w == 0x3F800000u)) bf32++;
            unsigned int h0 = w & 0xFFFFu, h1 = w >> 16;
            if (!((h0 == 0u || h0 == 0x3F80u) && (h1 == 0u || h1 == 0x3F80u))) bbf++;
            if (!((h0 == 0u || h0 == 0x3C00u) && (h1 == 0u || h1 == 0x3C00u))) bf16c++;
        }
        if (bi32) atomicAdd(&vi32, 1);
        if (bf32) atomicAdd(&vf32, 1);
        if (bbf)  atomicAdd(&vbf, 1);
        if (bf16c) atomicAdd(&vf16, 1);
        __syncthreads();
        if (threadIdx.x == 0) {
            int w;
            if (vi32 == 0) w = 4;
            else if (vf32 == 0) w = 4;
            else if (vbf == 0) w = 2;
            else if (vf16 == 0) w = 2;
            else w = 1;
            flags[16] = w;
        }
    }
}

// Pack mask (any width) to bytes: out[i] = (elem[i] != 0). 4 elems/thread.
__global__ void k_mask_bytes(const void* __restrict__ m, unsigned char* __restrict__ out,
                             long n, const int* __restrict__ widthFlag) {
    long i = ((long)blockIdx.x * 256 + threadIdx.x) * 4;
    if (i >= n) return;
    const int w = *widthFlag;
    unsigned int packed = 0;
    if (w == 4) {
        const unsigned int* p = (const unsigned int*)m;
#pragma unroll
        for (int u = 0; u < 4; ++u) packed |= (p[i + u] != 0u ? 1u : 0u) << (8 * u);
    } else if (w == 2) {
        const unsigned short* p = (const unsigned short*)m;
#pragma unroll
        for (int u = 0; u < 4; ++u) packed |= (p[i + u] != 0u ? 1u : 0u) << (8 * u);
    } else {
        const unsigned char* p = (const unsigned char*)m;
#pragma unroll
        for (int u = 0; u < 4; ++u) packed |= (p[i + u] != 0u ? 1u : 0u) << (8 * u);
    }
    *(unsigned int*)(out + i) = packed;
}

// ---------------------------------------------------------------------------
// Conv param precompute: kern [D,3] -> planar fp16 [3][D]; cbias -> fp16 [D];
// tanh(gate) -> float. One block.
struct ConvSrc { const void* kern[3]; const void* cb[3]; const void* gate[3]; };
__global__ void k_conv_params(ConvSrc p, const int* __restrict__ flags,
                              _Float16* __restrict__ out, float* __restrict__ tg, int D) {
#pragma unroll
    for (int t = 0; t < 3; ++t) {
        const int kIs = flags[6 + t], cIs = flags[13 + t];
        for (int d = threadIdx.x; d < D; d += 256) {
#pragma unroll
            for (int j = 0; j < 3; ++j)
                out[t * 3 * D + j * D + d] = (_Float16)rd(p.kern[t], (long)d * 3 + j, kIs);
            out[9 * D + t * D + d] = (_Float16)rd(p.cb[t], d, cIs);
        }
    }
    if (threadIdx.x < 3) {
        const void* g = p.gate[threadIdx.x];
        float gv = rd(g, 0, ((const unsigned int*)g)[0] == 0u ? 1 : 0);
        tg[threadIdx.x] = tanhf(gv);
    }
}

// ---------------------------------------------------------------------------
__device__ __forceinline__ h8 cvt8(const void* src, size_t off8, int isBf) {
    h8 d;
    if (isBf) {
        us8 s = *(const us8*)((const unsigned short*)src + off8 * 8);
#pragma unroll
        for (int u = 0; u < 8; ++u) d[u] = (_Float16)bf2f(s[u]);
    } else {
        const float* f = (const float*)src + off8 * 8;
        f4_t a = *(const f4_t*)f;
        f4_t b = *(const f4_t*)(f + 4);
#pragma unroll
        for (int u = 0; u < 4; ++u) { d[u] = (_Float16)a[u]; d[4 + u] = (_Float16)b[u]; }
    }
    return d;
}

__global__ void k_h_to_f16(const void* __restrict__ s0, const void* __restrict__ s1,
                           _Float16* __restrict__ dst, int n8each,
                           const int* __restrict__ flags) {
    int i = blockIdx.x * blockDim.x + threadIdx.x;
    if (i >= 2 * n8each) return;
    int seg = i / n8each, off = i - seg * n8each;
    h8 d = cvt8(seg ? s1 : s0, off, flags[seg]);
    *(h8*)(dst + (size_t)i * 8) = d;
}

struct Ptr4 { const void* p[4]; };
__global__ void k_w_to_f16(Ptr4 srcs, _Float16* __restrict__ dst, int n8each,
                           const int* __restrict__ flags) {
    int i = blockIdx.x * blockDim.x + threadIdx.x;
    if (i >= 4 * n8each) return;
    int seg = i / n8each, off = i - seg * n8each;
    h8 d = cvt8(srcs.p[seg], off, flags[seg]);
    *(h8*)(dst + (size_t)i * 8) = d;
}

// ---------------------------------------------------------------------------
// NT GEMM, MTILE x 128 x BK=64 tiles (MTILE = 128 or 64), 4 waves/block.
// LDS rows hold 64 fp16 = 8 segs of 16B; physical seg p = (seg + row) & 7
// -> fragment-read start banks 4*((t*4+lq+lr)&7): 8 banks x 2 lanes/phase
// (conflict-free, same family as the measured-0 BK=32 swizzle).
// Staging permutes segs within each row's 128B window (coalescing kept;
// LDS dest = wave-uniform base + lane*16 contract intact).
// XCD-aware 1D decode. __launch_bounds__(256,4) caps VGPR<=128 (occupancy).
// MODE 0: fp16 out            MODE 1: fp16 out + bias (bias2 = 2nd N-half)
// MODE 2: fp32 out + bias     MODE 3: fp16 scores (scale + byte-mask)
template <int MODE, int MTILE>
__global__ __launch_bounds__(256, 4) void k_gemm_nt(
    const _Float16* __restrict__ A, const _Float16* __restrict__ Bm,
    void* __restrict__ Cout,
    const void* __restrict__ bias, const int* __restrict__ biasFlag,
    const void* __restrict__ bias2, const int* __restrict__ biasFlag2,
    int N, int K, long sA, long sB, long sC,
    float scale, const unsigned char* __restrict__ mask8,
    int NT, int BZ) {

    constexpr int NI = (MTILE == 128) ? 4 : 2;
    constexpr int NCA = MTILE / 32;            // A chunks per thread (4 or 2)
    __shared__ __align__(16) _Float16 As[MTILE * 64];
    __shared__ __align__(16) _Float16 Bs[128 * 64];

    const long id = blockIdx.x;
    const int xcd = (int)(id & 7);
    const long local = id >> 3;
    const int col = (int)(local % NT);
    const long g = (local / NT) * 8 + xcd;
    const int bz = (int)(g % BZ);
    const int brow = (int)(g / BZ);

    const int tid  = threadIdx.x;
    const int wave = tid >> 6, lane = tid & 63;
    const int wm = (wave >> 1) * (MTILE / 2), wn = (wave & 1) * 64;
    const int lr = lane & 15, lq = lane >> 4;

    const _Float16* Ab = A + (long)bz * sA + (size_t)brow * MTILE * K;
    const _Float16* Bb = Bm + (long)bz * sB + (size_t)col * 128 * K;

    f4_t acc[NI][4] = {};

    // staging: LDS chunk c (16B) holds global (row=c>>3, seg=((c&7)-(c>>3))&7)
    const _Float16* gA[NCA];
    _Float16* lA[NCA];
#pragma unroll
    for (int j = 0; j < NCA; ++j) {
        int c = tid + j * 256;
        int r = c >> 3, s = ((c & 7) - r) & 7;
        gA[j] = Ab + (size_t)r * K + s * 8;
        lA[j] = As + c * 8;
    }
    const _Float16* gB[4];
    _Float16* lB[4];
#pragma unroll
    for (int j = 0; j < 4; ++j) {
        int c = tid + j * 256;
        int r = c >> 3, s = ((c & 7) - r) & 7;
        gB[j] = Bb + (size_t)r * K + s * 8;
        lB[j] = Bs + c * 8;
    }

    for (int kb = 0; kb < K; kb += 64) {
#pragma unroll
        for (int j = 0; j < NCA; ++j)
            __builtin_amdgcn_global_load_lds((void GLOBAL_AS*)(gA[j] + kb), (void LDS_AS*)lA[j], 16, 0, 0);
#pragma unroll
        for (int j = 0; j < 4; ++j)
            __builtin_amdgcn_global_load_lds((void GLOBAL_AS*)(gB[j] + kb), (void LDS_AS*)lB[j], 16, 0, 0);
        __syncthreads();

#pragma unroll
        for (int t = 0; t < 2; ++t) {
            const int fs = ((t * 4 + lq + lr) & 7) * 8;   // row&7 == lr&7
            h8 af[NI], bfr[4];
#pragma unroll
            for (int i = 0; i < NI; ++i) af[i]  = *(const h8*)&As[(wm + i * 16 + lr) * 64 + fs];
#pragma unroll
            for (int j = 0; j < 4; ++j) bfr[j] = *(const h8*)&Bs[(wn + j * 16 + lr) * 64 + fs];
#pragma unroll
            for (int i = 0; i < NI; ++i)
#pragma unroll
                for (int j = 0; j < 4; ++j)
                    acc[i][j] = __builtin_amdgcn_mfma_f32_16x16x32_f16(af[i], bfr[j], acc[i][j], 0, 0, 0);
        }
        __syncthreads();
    }

    // epilogue: C/D layout col=lane&15, row=(lane>>4)*4+reg
    const long row0 = (long)brow * MTILE + wm + lq * 4;
    const long col0 = (long)col * 128 + wn + lr;

    if constexpr (MODE == 3) {
        _Float16* C = (_Float16*)Cout + (long)bz * sC;
#pragma unroll
        for (int i = 0; i < NI; ++i)
#pragma unroll
            for (int j = 0; j < 4; ++j)
#pragma unroll
                for (int r = 0; r < 4; ++r) {
                    long row = row0 + i * 16 + r;
                    long ccol = col0 + j * 16;
                    bool keep = mask8[row * (long)N + ccol] != 0;
                    float v = acc[i][j][r] * scale;
                    v = fminf(fmaxf(v, -60000.0f), 60000.0f);
                    C[row * (long)N + ccol] = (_Float16)(keep ? v : -60000.0f);
                }
    } else {
        float bv[4];
        if constexpr (MODE != 0) {
            const void* bp = bias; const int* bfp = biasFlag; long boff = 0;
            if (bias2 != nullptr && col * 128 >= (N >> 1)) {
                bp = bias2; bfp = biasFlag2; boff = (long)(N >> 1);
            }
            const int bIs = *bfp;
#pragma unroll
            for (int j = 0; j < 4; ++j) bv[j] = rd(bp, col0 + j * 16 - boff, bIs);
        } else {
#pragma unroll
            for (int j = 0; j < 4; ++j) bv[j] = 0.0f;
        }
        if constexpr (MODE == 2) {
            float* C = (float*)Cout + (long)bz * sC;
#pragma unroll
            for (int i = 0; i < NI; ++i)
#pragma unroll
                for (int j = 0; j < 4; ++j)
#pragma unroll
                    for (int r = 0; r < 4; ++r)
                        C[(row0 + i * 16 + r) * (long)N + col0 + j * 16] = acc[i][j][r] + bv[j];
        } else {
            _Float16* C = (_Float16*)Cout + (long)bz * sC;
#pragma unroll
            for (int i = 0; i < NI; ++i)
#pragma unroll
                for (int j = 0; j < 4; ++j)
#pragma unroll
                    for (int r = 0; r < 4; ++r) {
                        float v = acc[i][j][r] + bv[j];
                        v = fminf(fmaxf(v, -65000.0f), 65000.0f);
                        C[(row0 + i * 16 + r) * (long)N + col0 + j * 16] = (_Float16)v;
                    }
        }
    }
}

// ---------------------------------------------------------------------------
// Gated depthwise conv for q and k in one launch; planar fp16 params.
struct ConvP {
    const _Float16* x; int xs; _Float16* y;
    const _Float16* kp; const _Float16* cb; const float* tg;
};
__global__ void k_dwconv2(ConvP p0, ConvP p1, int S, int D) {
    const ConvP& p = blockIdx.z ? p1 : p0;
    int s = blockIdx.x, b = blockIdx.y;
    int d0 = threadIdx.x * 8;
    const size_t xb = ((size_t)b * S + s) * p.xs + d0;
    const size_t yb = ((size_t)b * S + s) * D + d0;
    h8 zero;
#pragma unroll
    for (int u = 0; u < 8; ++u) zero[u] = (_Float16)0.0f;
    h8 xc = *(const h8*)(p.x + xb);
    h8 xp = (s > 0)     ? *(const h8*)(p.x + xb - p.xs) : zero;
    h8 xn = (s < S - 1) ? *(const h8*)(p.x + xb + p.xs) : zero;
    h8 k0 = *(const h8*)(p.kp + 0 * D + d0);
    h8 k1 = *(const h8*)(p.kp + 1 * D + d0);
    h8 k2 = *(const h8*)(p.kp + 2 * D + d0);
    h8 cb = *(const h8*)(p.cb + d0);
    float tg = *p.tg;
    h8 o;
#pragma unroll
    for (int u = 0; u < 8; ++u) {
        float cv = (float)xp[u] * (float)k0[u] + (float)xc[u] * (float)k1[u] +
                   (float)xn[u] * (float)k2[u] + (float)cb[u];
        float v = (float)xc[u] + tg * cv;
        o[u] = (_Float16)fminf(fmaxf(v, -65000.0f), 65000.0f);
    }
    *(h8*)(p.y + yb) = o;
}

// ---------------------------------------------------------------------------
// Fused dwconv_v + transpose: x = lin_kv+D (stride 2D), y = vt [B,D,SK].
// vt MUST NOT alias lin_kv. Planar fp16 params.
__global__ void k_dwconv_t(const _Float16* __restrict__ x, int xs,
                           _Float16* __restrict__ vt,
                           const _Float16* __restrict__ kp,
                           const _Float16* __restrict__ cbp,
                           const float* __restrict__ tgp,
                           int SK, int D) {
    __shared__ _Float16 T[64][65];
    int b = blockIdx.z;
    int s0 = blockIdx.x * 64, d0 = blockIdx.y * 64;
    int tid = threadIdx.x;
    float tg = *tgp;
    h8 zero;
#pragma unroll
    for (int u = 0; u < 8; ++u) zero[u] = (_Float16)0.0f;
#pragma unroll
    for (int it = 0; it < 2; ++it) {
        int idx = it * 256 + tid;
        int r = idx >> 3, c = (idx & 7) * 8;
        int s = s0 + r;
        const size_t xb = ((size_t)b * SK + s) * xs + d0 + c;
        h8 xc = *(const h8*)(x + xb);
        h8 xp = (s > 0)      ? *(const h8*)(x + xb - xs) : zero;
        h8 xn = (s < SK - 1) ? *(const h8*)(x + xb + xs) : zero;
        h8 k0 = *(const h8*)(kp + 0 * D + d0 + c);
        h8 k1 = *(const h8*)(kp + 1 * D + d0 + c);
        h8 k2 = *(const h8*)(kp + 2 * D + d0 + c);
        h8 cb = *(const h8*)(cbp + d0 + c);
#pragma unroll
        for (int u = 0; u < 8; ++u) {
            float cv = (float)xp[u] * (float)k0[u] + (float)xc[u] * (float)k1[u] +
                       (float)xn[u] * (float)k2[u] + (float)cb[u];
            float v = (float)xc[u] + tg * cv;
            T[r][c + u] = (_Float16)fminf(fmaxf(v, -65000.0f), 65000.0f);
        }
    }
    __syncthreads();
#pragma unroll
    for (int it = 0; it < 2; ++it) {
        int idx = it * 256 + tid;
        int dr = idx >> 3, c = (idx & 7) * 8;
        h8 o;
#pragma unroll
        for (int u = 0; u < 8; ++u) o[u] = T[c + u][dr];
        *(h8*)(vt + ((size_t)b * D + d0 + dr) * SK + s0 + c) = o;
    }
}

// ---------------------------------------------------------------------------
// Row softmax over SK=2048 fp16 scores; one 256-thread block per row.
__global__ __launch_bounds__(256) void k_softmax(const _Float16* __restrict__ sc,
                                                 _Float16* __restrict__ pr, int SK) {
    const long row = blockIdx.x;
    const int tid = threadIdx.x, lane = tid & 63, wave = tid >> 6;
    h8 v = *(const h8*)(sc + row * (long)SK + tid * 8);
    float f[8]; float mx = -3.0e38f;
#pragma unroll
    for (int u = 0; u < 8; ++u) { f[u] = (float)v[u]; mx = fmaxf(mx, f[u]); }
#pragma unroll
    for (int o = 32; o > 0; o >>= 1) mx = fmaxf(mx, __shfl_xor(mx, o, 64));
    __shared__ float red[8];
    if (lane == 0) red[wave] = mx;
    __syncthreads();
    mx = fmaxf(fmaxf(red[0], red[1]), fmaxf(red[2], red[3]));
    float sum = 0.0f;
#pragma unroll
    for (int u = 0; u < 8; ++u) { f[u] = __expf(f[u] - mx); sum += f[u]; }
#pragma unroll
    for (int o = 32; o > 0; o >>= 1) sum += __shfl_xor(sum, o, 64);
    if (lane == 0) red[4 + wave] = sum;
    __syncthreads();
    sum = red[4] + red[5] + red[6] + red[7];
    float inv = 1.0f / sum;
    h8 o8;
#pragma unroll
    for (int u = 0; u < 8; ++u) o8[u] = (_Float16)(f[u] * inv);
    *(h8*)(pr + row * (long)SK + tid * 8) = o8;
}

// ---------------------------------------------------------------------------
extern "C" void kernel_launch(void* const* d_in, const int* in_sizes, int n_in,
                              void* d_out, int out_size, void* d_ws, size_t ws_size,
                              hipStream_t stream) {
    const int Bn = 4, SQ = 2048, SK = 2048, D = 1024;
    const size_t nQ = (size_t)Bn * SQ * D;   // 8,388,608
    const long   nM = (long)SQ * SK;         // 4,194,304 mask elements

    const void* qh = d_in[0];
    const void* mh = d_in[1];
    const void* mask = d_in[2];
    const void* q_w = d_in[3];
    const void* q_b = d_in[4];
    const void* k_w = d_in[5];
    const void* k_b = d_in[6];
    const void* v_w = d_in[7];
    const void* v_b = d_in[8];
    const void* o_w = d_in[9];
    const void* o_b = d_in[10];
    const void* q_kern = d_in[11];
    const void* q_cb   = d_in[12];
    const void* q_g    = d_in[13];
    const void* k_kern = d_in[14];
    const void* k_cb   = d_in[15];
    const void* k_g    = d_in[16];
    const void* v_kern = d_in[17];
    const void* v_cb   = d_in[18];
    const void* v_g    = d_in[19];

    // ---- workspace layout (lifetime-overlaid) ----
    // [0,33.5MB)        scores -> attn_out
    // [33.5,41.9MB)     w16 x4; after kv-proj: mask8 slots 0-1, conv params slot 2
    // [41.9,92.3MB)     lin_q + lin_kv; probs overlays after convs
    // [92.3,125.8MB)    qh16/mh16 staging -> conv_q, conv_k
    // [125.8,142.6MB)   vt  (must NOT alias lin_kv)
    // [142.6MB+)        flags
    char* ws = (char*)d_ws;
    _Float16* scores   = (_Float16*)(ws + 0);
    _Float16* attn_out = (_Float16*)(ws + 0);
    _Float16* w16      = (_Float16*)(ws + 33554432);
    unsigned char* mask8 = (unsigned char*)(ws + 33554432);
    _Float16* par16    = (_Float16*)(ws + 37748736);
    float*    tgf      = (float*)(ws + 37748736 + 12 * 1024 * 2);
    _Float16* lin      = (_Float16*)(ws + 41943040);
    _Float16* lin_q    = lin;
    _Float16* lin_kv   = lin + nQ;
    _Float16* probs    = lin;
    _Float16* conv     = (_Float16*)(ws + 92274688);
    _Float16* qh16     = conv;
    _Float16* mh16     = conv + nQ;
    _Float16* vt       = (_Float16*)(ws + 125829120);
    int*      flags    = (int*)(ws + 142606336);

    // 0. probes (merged)
    Probe16 pa;
    const void* pp[16] = {qh, mh, q_w, k_w, v_w, o_w, q_kern, k_kern, v_kern,
                          q_b, k_b, v_b, o_b, q_cb, k_cb, v_cb};
    const int   pn[16] = {2048, 2048, 2048, 2048, 2048, 2048, 3072, 3072, 3072,
                          1024, 1024, 1024, 1024, 1024, 1024, 1024};
    for (int i = 0; i < 16; ++i) { pa.p[i] = (const unsigned short*)pp[i]; pa.n[i] = pn[i]; }
    k_probes<<<17, 256, 0, stream>>>(pa, (const unsigned int*)mask, flags);

    // 1. converts -> fp16
    const int nH8 = (int)(nQ / 8);
    k_h_to_f16<<<(2 * nH8 + 255) / 256, 256, 0, stream>>>(qh, mh, qh16, nH8, flags + 0);
    const int nW8 = D * D / 8;
    Ptr4 wp; wp.p[0] = q_w; wp.p[1] = k_w; wp.p[2] = v_w; wp.p[3] = o_w;
    k_w_to_f16<<<(4 * nW8 + 255) / 256, 256, 0, stream>>>(wp, w16, nW8, flags + 2);

    // 2. projections
    k_gemm_nt<1, 64><<<dim3(1024), 256, 0, stream>>>(
        qh16, w16, lin_q, q_b, flags + 9, nullptr, nullptr,
        D, D, 0, 0, 0, 1.0f, nullptr, 8, 1);
    k_gemm_nt<1, 128><<<dim3(1024), 256, 0, stream>>>(
        mh16, w16 + (size_t)D * D, lin_kv, k_b, flags + 10, v_b, flags + 11,
        2 * D, D, 0, 0, 0, 1.0f, nullptr, 16, 1);

    // 2b. pack mask + conv params into the now-dead w16 slots
    k_mask_bytes<<<(int)(nM / 4 / 256), 256, 0, stream>>>(mask, mask8, nM, flags + 16);
    ConvSrc cs;
    cs.kern[0] = q_kern; cs.kern[1] = k_kern; cs.kern[2] = v_kern;
    cs.cb[0] = q_cb; cs.cb[1] = k_cb; cs.cb[2] = v_cb;
    cs.gate[0] = q_g; cs.gate[1] = k_g; cs.gate[2] = v_g;
    k_conv_params<<<1, 256, 0, stream>>>(cs, flags, par16, tgf, D);

    // 3. gated depthwise conv: q + k in one launch; v fused with transpose
    ConvP cq{lin_q, D, conv + 0 * nQ, par16 + 0 * 3 * D, par16 + 9 * D + 0 * D, tgf + 0};
    ConvP ck{lin_kv, 2 * D, conv + 1 * nQ, par16 + 1 * 3 * D, par16 + 9 * D + 1 * D, tgf + 1};
    k_dwconv2<<<dim3(SQ, Bn, 2), 128, 0, stream>>>(cq, ck, SQ, D);
    k_dwconv_t<<<dim3(SK / 64, D / 64, Bn), 256, 0, stream>>>(
        lin_kv + D, 2 * D, vt, par16 + 2 * 3 * D, par16 + 9 * D + 2 * D, tgf + 2, SK, D);

    // 5. scores: per-batch M=2048(128:16), N=2048 (NT=16), BZ=4 -> 1024 blocks
    k_gemm_nt<3, 128><<<dim3(1024), 256, 0, stream>>>(
        conv + 0 * nQ, conv + 1 * nQ, scores, nullptr, nullptr, nullptr, nullptr,
        SK, D, (long)SQ * D, (long)SK * D, (long)SQ * SK, 0.03125f, mask8, 16, 4);

    // 6. softmax
    k_softmax<<<Bn * SQ, 256, 0, stream>>>(scores, probs, SK);

    // 7. attn @ v: per-batch M=2048(64:32), N=1024 (NT=8), BZ=4 -> 1024 blocks
    k_gemm_nt<0, 64><<<dim3(1024), 256, 0, stream>>>(
        probs, vt, attn_out, nullptr, nullptr, nullptr, nullptr,
        D, SK, (long)SQ * SK, (long)D * SK, (long)SQ * D, 1.0f, nullptr, 8, 4);

    // 8. out-proj: M=8192(64:128), N=1024 (NT=8), BZ=1 -> 1024 blocks, fp32 out
    k_gemm_nt<2, 64><<<dim3(1024), 256, 0, stream>>>(
        attn_out, w16 + 3 * (size_t)D * D, d_out, o_b, flags + 12, nullptr, nullptr,
        D, D, 0, 0, 0, 1.0f, nullptr, 8, 1);

    (void)in_sizes; (void)n_in; (void)out_size; (void)ws_size;
}